// Round 1
// baseline (638.549 us; speedup 1.0000x reference)
//
#include <hip/hip_runtime.h>
#include <math.h>

#define BSZ 4
#define SSZ 1024
#define EMBD 128
#define HN 4
#define DN 32
#define TQ (SSZ - 1)

// ---------------------------------------------------------------------------
// Kernel 1: gather embeddings, project to Q/K/V (+inter), compute sr = scale*Q.K
// One block per token, 128 threads (thread j = output column j).
// Q/K/V stored in [b][h][s][d] layout so attention reads contiguous 128B rows.
// ---------------------------------------------------------------------------
__global__ __launch_bounds__(128)
void embed_project_kernel(const int* __restrict__ idx, const int* __restrict__ flg,
                          const float* __restrict__ item_emb, const float* __restrict__ ans_emb,
                          const float* __restrict__ Wq, const float* __restrict__ bq,
                          const float* __restrict__ Wk, const float* __restrict__ bk,
                          const float* __restrict__ Wv, const float* __restrict__ bv,
                          const float* __restrict__ Wh, const float* __restrict__ bh,
                          float* __restrict__ Qt, float* __restrict__ Kt, float* __restrict__ Vt,
                          float* __restrict__ ecache, float* __restrict__ srw)
{
    __shared__ float es[EMBD], as_[EMBD], inters[EMBD];
    const int tok = blockIdx.x;
    const int b = tok >> 10;
    const int s = tok & 1023;
    const int j = threadIdx.x;

    es[j]  = item_emb[idx[tok] * EMBD + j];
    as_[j] = ans_emb[flg[tok] * EMBD + j];
    __syncthreads();

    // inter = concat(e, a) @ Wh + bh
    float accI = bh[j];
    #pragma unroll 4
    for (int i = 0; i < EMBD; i++) accI = fmaf(es[i],  Wh[i * EMBD + j], accI);
    #pragma unroll 4
    for (int i = 0; i < EMBD; i++) accI = fmaf(as_[i], Wh[(EMBD + i) * EMBD + j], accI);

    float accQ = bq[j], accK = bk[j];
    #pragma unroll 4
    for (int i = 0; i < EMBD; i++) {
        float ev = es[i];
        accQ = fmaf(ev, Wq[i * EMBD + j], accQ);
        accK = fmaf(ev, Wk[i * EMBD + j], accK);
    }
    inters[j] = accI;
    __syncthreads();

    float accV = bv[j];
    #pragma unroll 4
    for (int i = 0; i < EMBD; i++) accV = fmaf(inters[i], Wv[i * EMBD + j], accV);

    const int h = j >> 5, d = j & 31;
    const int qidx = (((b * HN + h) * SSZ) + s) * DN + d;
    Qt[qidx] = accQ;
    Kt[qidx] = accK;
    Vt[qidx] = accV;
    ecache[tok * EMBD + j] = es[j];

    // sr[b,h,s] = scale * sum_d Q[h,d]*K[h,d]  (reduce within each 32-lane head group)
    float p = accQ * accK;
    #pragma unroll
    for (int msk = 16; msk >= 1; msk >>= 1) p += __shfl_xor(p, msk, 64);
    if ((j & 31) == 0) srw[(b * HN + h) * SSZ + s] = p * 0.17677669529663687f;
}

// ---------------------------------------------------------------------------
// Kernel 2: per (b,h): max over s, ex = exp(sr-max), inclusive cumsum -> Ep.
//           per b (h==0 blocks): cumsum of max(gaps,1) -> Pp.
// One block per (b,h), 1024 threads. Hillis-Steele scan in LDS.
// ---------------------------------------------------------------------------
__global__ __launch_bounds__(1024)
void scan_kernel(const float* __restrict__ srw, const float* __restrict__ gaps,
                 float* __restrict__ Ep, float* __restrict__ Pp)
{
    __shared__ float buf[SSZ];
    __shared__ float red[16];
    const int b = blockIdx.x >> 2, h = blockIdx.x & 3;
    const int tid = threadIdx.x;

    float v = srw[(b * HN + h) * SSZ + tid];
    // block max
    float wm = v;
    #pragma unroll
    for (int msk = 32; msk >= 1; msk >>= 1) wm = fmaxf(wm, __shfl_xor(wm, msk, 64));
    if ((tid & 63) == 0) red[tid >> 6] = wm;
    __syncthreads();
    if (tid == 0) {
        float mm = red[0];
        for (int k = 1; k < 16; k++) mm = fmaxf(mm, red[k]);
        red[0] = mm;
    }
    __syncthreads();
    const float mx = red[0];

    float ex = __expf(v - mx);
    buf[tid] = ex;
    __syncthreads();
    for (int off = 1; off < SSZ; off <<= 1) {
        float tv = (tid >= off) ? buf[tid - off] : 0.0f;
        __syncthreads();
        buf[tid] += tv;
        __syncthreads();
    }
    Ep[(b * HN + h) * (SSZ + 1) + tid + 1] = buf[tid];
    if (tid == 0) Ep[(b * HN + h) * (SSZ + 1)] = 0.0f;

    if (h == 0) {
        float gv = fmaxf(gaps[b * SSZ + tid], 1.0f);
        __syncthreads();
        buf[tid] = gv;
        __syncthreads();
        for (int off = 1; off < SSZ; off <<= 1) {
            float tv = (tid >= off) ? buf[tid - off] : 0.0f;
            __syncthreads();
            buf[tid] += tv;
            __syncthreads();
        }
        Pp[b * (SSZ + 1) + tid + 1] = buf[tid];
        if (tid == 0) Pp[b * (SSZ + 1)] = 0.0f;
    }
}

// ---------------------------------------------------------------------------
// Kernel 3: decayed attention + fused MLP epilogue.
// One block per (b, t). 256 threads = 4 waves; wave h handles head h.
// Lane owns keys i = lane, lane+64, ...; online softmax; butterfly merge.
// Then 128 threads compute h1 = relu([ctx;e] @ W1 + b1), logit = h1.W2 + b2.
// ---------------------------------------------------------------------------
__global__ __launch_bounds__(256)
void attn_kernel(const float* __restrict__ Qt, const float* __restrict__ Kt,
                 const float* __restrict__ Vt,
                 const float* __restrict__ Ep, const float* __restrict__ Pp,
                 const float* __restrict__ theta_raw, const float* __restrict__ ecache,
                 const float* __restrict__ W1, const float* __restrict__ b1,
                 const float* __restrict__ W2, const float* __restrict__ b2,
                 float* __restrict__ out)
{
    __shared__ float qs[EMBD];
    __shared__ float ctx_s[EMBD];
    __shared__ float esm[EMBD];
    __shared__ float red[EMBD];

    const int bt = blockIdx.x;
    const int b = bt / TQ;
    const int t = bt - b * TQ + 1;   // query position 1..S-1
    const int tid = threadIdx.x;
    const int h = tid >> 6, lane = tid & 63;

    if (tid < EMBD) {
        const int hh = tid >> 5, d = tid & 31;
        qs[tid]  = Qt[(((b * HN + hh) * SSZ) + t) * DN + d];
        esm[tid] = ecache[(b * SSZ + t) * EMBD + tid];
    }
    __syncthreads();

    const float theta = logf(1.0f + __expf(theta_raw[h])) + 1e-4f;
    const float* Epb = Ep + (b * HN + h) * (SSZ + 1);
    const float* Ppb = Pp + b * (SSZ + 1);
    const float Ep_t = Epb[t], Pp_t = Ppb[t];
    const float inv_Ept = 1.0f / Ep_t;
    const float4* Kb = (const float4*)(Kt + ((b * HN + h) * SSZ) * DN);
    const float4* Vb = (const float4*)(Vt + ((b * HN + h) * SSZ) * DN);
    const float scale = 0.17677669529663687f;

    float q[DN];
    #pragma unroll
    for (int d = 0; d < DN; d++) q[d] = qs[h * DN + d];

    float m = -3e38f, l = 0.0f;
    float acc[DN];
    #pragma unroll
    for (int d = 0; d < DN; d++) acc[d] = 0.0f;

    for (int i = lane; i < t; i += 64) {
        float dot = 0.0f;
        #pragma unroll
        for (int c = 0; c < 8; c++) {
            float4 kv = Kb[i * 8 + c];
            dot += kv.x * q[4*c] + kv.y * q[4*c+1] + kv.z * q[4*c+2] + kv.w * q[4*c+3];
        }
        const float raw = dot * scale;
        const float pdv = (float)(t - i) * (Pp_t - Ppb[i]) * ((Ep_t - Epb[i]) * inv_Ept);
        const float sc  = raw * __expf(-theta * pdv);

        const float mnew  = fmaxf(m, sc);
        const float alpha = __expf(m - mnew);
        const float p     = __expf(sc - mnew);
        l = l * alpha + p;
        #pragma unroll
        for (int c = 0; c < 8; c++) {
            float4 vv = Vb[i * 8 + c];
            acc[4*c]   = fmaf(p, vv.x, acc[4*c]   * alpha);
            acc[4*c+1] = fmaf(p, vv.y, acc[4*c+1] * alpha);
            acc[4*c+2] = fmaf(p, vv.z, acc[4*c+2] * alpha);
            acc[4*c+3] = fmaf(p, vv.w, acc[4*c+3] * alpha);
        }
        m = mnew;
    }

    // 64-lane butterfly merge of (m, l, acc[])
    #pragma unroll
    for (int msk = 32; msk >= 1; msk >>= 1) {
        const float m2 = __shfl_xor(m, msk, 64);
        const float l2 = __shfl_xor(l, msk, 64);
        const float mn = fmaxf(m, m2);
        const float a1 = __expf(m - mn), a2 = __expf(m2 - mn);
        l = l * a1 + l2 * a2;
        #pragma unroll
        for (int d = 0; d < DN; d++) {
            const float o = __shfl_xor(acc[d], msk, 64);
            acc[d] = acc[d] * a1 + o * a2;
        }
        m = mn;
    }
    if (lane == 0) {
        const float invl = 1.0f / l;
        #pragma unroll
        for (int d = 0; d < DN; d++) ctx_s[h * DN + d] = acc[d] * invl;
    }
    __syncthreads();

    // MLP epilogue: feat = [ctx (128) ; e (128)] ; h1 = relu(feat@W1+b1); logit = h1.W2+b2
    if (tid < EMBD) {
        float a = b1[tid];
        #pragma unroll 4
        for (int i = 0; i < EMBD; i++) a = fmaf(ctx_s[i], W1[i * EMBD + tid], a);
        #pragma unroll 4
        for (int i = 0; i < EMBD; i++) a = fmaf(esm[i], W1[(EMBD + i) * EMBD + tid], a);
        const float h1 = fmaxf(a, 0.0f);
        red[tid] = h1 * W2[tid];
    }
    __syncthreads();
    if (tid < 64) red[tid] += red[tid + 64];
    __syncthreads();
    if (tid < 64) {
        float rv = red[tid];
        #pragma unroll
        for (int msk = 32; msk >= 1; msk >>= 1) rv += __shfl_xor(rv, msk, 64);
        if (tid == 0) {
            const float logit = rv + b2[0];
            out[b * TQ + (t - 1)] = 1.0f / (1.0f + __expf(-logit));
            out[BSZ * TQ + b * TQ + (t - 1)] = 1.0f;   // valid flag
        }
    }
}

// ---------------------------------------------------------------------------
extern "C" void kernel_launch(void* const* d_in, const int* in_sizes, int n_in,
                              void* d_out, int out_size, void* d_ws, size_t ws_size,
                              hipStream_t stream)
{
    const int*   idx       = (const int*)d_in[0];
    const int*   flg       = (const int*)d_in[1];
    const float* gaps      = (const float*)d_in[2];
    const float* item_emb  = (const float*)d_in[3];
    const float* ans_emb   = (const float*)d_in[4];
    const float* Wq        = (const float*)d_in[5];
    const float* bq        = (const float*)d_in[6];
    const float* Wk        = (const float*)d_in[7];
    const float* bk        = (const float*)d_in[8];
    const float* Wv        = (const float*)d_in[9];
    const float* bv        = (const float*)d_in[10];
    const float* Wh        = (const float*)d_in[11];
    const float* bh        = (const float*)d_in[12];
    const float* W1        = (const float*)d_in[13];
    const float* b1        = (const float*)d_in[14];
    const float* W2        = (const float*)d_in[15];
    const float* b2        = (const float*)d_in[16];
    const float* theta_raw = (const float*)d_in[17];

    // workspace carve-up (floats): ~8.5 MB total
    float* ws  = (float*)d_ws;
    float* Qt  = ws;                      // B*H*S*D = 524288
    float* Kt  = Qt + BSZ * HN * SSZ * DN;
    float* Vt  = Kt + BSZ * HN * SSZ * DN;
    float* ec  = Vt + BSZ * HN * SSZ * DN;   // B*S*EMB = 524288
    float* srw = ec + BSZ * SSZ * EMBD;      // B*H*S = 16384
    float* Ep  = srw + BSZ * HN * SSZ;       // B*H*(S+1) -> pad 16416
    float* Pp  = Ep + 16416;                 // B*(S+1) = 4100

    float* out = (float*)d_out;

    embed_project_kernel<<<BSZ * SSZ, 128, 0, stream>>>(
        idx, flg, item_emb, ans_emb, Wq, bq, Wk, bk, Wv, bv, Wh, bh,
        Qt, Kt, Vt, ec, srw);
    scan_kernel<<<BSZ * HN, 1024, 0, stream>>>(srw, gaps, Ep, Pp);
    attn_kernel<<<BSZ * TQ, 256, 0, stream>>>(
        Qt, Kt, Vt, Ep, Pp, theta_raw, ec, W1, b1, W2, b2, out);
}

// Round 2
// 560.701 us; speedup vs baseline: 1.1388x; 1.1388x over previous
//
#include <hip/hip_runtime.h>
#include <math.h>

#define BSZ 4
#define SSZ 1024
#define EMBD 128
#define HN 4
#define DN 32
#define TQ (SSZ - 1)   // 1023 queries per batch
#define NROWS (BSZ * TQ)  // 4092

// ---------------------------------------------------------------------------
// Kernel 1: embed + project. 16 tokens per block, 256 threads.
// Thread = (col j = tid&127, half hf = tid>>7); each thread computes col j of
// Q/K/V/inter for 8 tokens (register-tiled: weight loaded once per 8 tokens).
// ---------------------------------------------------------------------------
#define TT 16
__global__ __launch_bounds__(256)
void embed2_kernel(const int* __restrict__ idx, const int* __restrict__ flg,
                   const float* __restrict__ item_emb, const float* __restrict__ ans_emb,
                   const float* __restrict__ Wq, const float* __restrict__ bq,
                   const float* __restrict__ Wk, const float* __restrict__ bk,
                   const float* __restrict__ Wv, const float* __restrict__ bv,
                   const float* __restrict__ Wh, const float* __restrict__ bh,
                   float* __restrict__ Qt, float* __restrict__ Kt, float* __restrict__ Vt,
                   float* __restrict__ ec, float* __restrict__ srw)
{
    __shared__ float es[TT][132], as2[TT][132], inters[TT][132];
    const int tid = threadIdx.x;
    const int tok0 = blockIdx.x * TT;

    // stage e and a rows (16 tokens x 128 floats each), also write ecache
    #pragma unroll
    for (int r = 0; r < 2; r++) {
        const int tk = r * 8 + (tid >> 5);   // 0..15
        const int v4 = tid & 31;             // float4 index 0..31
        const int tok = tok0 + tk;
        const float4 ev = ((const float4*)(item_emb + idx[tok] * EMBD))[v4];
        const float4 av = ((const float4*)(ans_emb  + flg[tok] * EMBD))[v4];
        *((float4*)(&es[tk][v4 * 4]))  = ev;
        *((float4*)(&as2[tk][v4 * 4])) = av;
        *((float4*)(ec + tok * EMBD + v4 * 4)) = ev;
    }
    __syncthreads();

    const int j  = tid & 127;
    const int hf = tid >> 7;      // 0 or 1
    const int T0 = hf * 8;

    // inter = [e;a] @ Wh + bh   (8 tokens per thread)
    float aI[8];
    {
        const float bhj = bh[j];
        #pragma unroll
        for (int k = 0; k < 8; k++) aI[k] = bhj;
    }
    for (int i = 0; i < 128; i++) {
        const float w = Wh[i * EMBD + j];
        #pragma unroll
        for (int k = 0; k < 8; k++) aI[k] = fmaf(es[T0 + k][i], w, aI[k]);
    }
    for (int i = 0; i < 128; i++) {
        const float w = Wh[(128 + i) * EMBD + j];
        #pragma unroll
        for (int k = 0; k < 8; k++) aI[k] = fmaf(as2[T0 + k][i], w, aI[k]);
    }

    // Q, K
    float aQ[8], aK[8];
    {
        const float bqj = bq[j], bkj = bk[j];
        #pragma unroll
        for (int k = 0; k < 8; k++) { aQ[k] = bqj; aK[k] = bkj; }
    }
    for (int i = 0; i < 128; i++) {
        const float wq = Wq[i * EMBD + j];
        const float wk = Wk[i * EMBD + j];
        #pragma unroll
        for (int k = 0; k < 8; k++) {
            const float e = es[T0 + k][i];
            aQ[k] = fmaf(e, wq, aQ[k]);
            aK[k] = fmaf(e, wk, aK[k]);
        }
    }

    #pragma unroll
    for (int k = 0; k < 8; k++) inters[T0 + k][j] = aI[k];
    __syncthreads();

    // V = inter @ Wv + bv
    float aV[8];
    {
        const float bvj = bv[j];
        #pragma unroll
        for (int k = 0; k < 8; k++) aV[k] = bvj;
    }
    for (int i = 0; i < 128; i++) {
        const float w = Wv[i * EMBD + j];
        #pragma unroll
        for (int k = 0; k < 8; k++) aV[k] = fmaf(inters[T0 + k][i], w, aV[k]);
    }

    // stores + sr
    const int b = tok0 >> 10;
    const int h = j >> 5, d = j & 31;
    const int bh_ = b * HN + h;
    const float scale = 0.17677669529663687f;
    #pragma unroll
    for (int k = 0; k < 8; k++) {
        const int s = (tok0 & 1023) + T0 + k;
        const int qi = (bh_ * SSZ + s) * DN + d;
        Qt[qi] = aQ[k]; Kt[qi] = aK[k]; Vt[qi] = aV[k];
        float p = aQ[k] * aK[k];
        #pragma unroll
        for (int msk = 16; msk >= 1; msk >>= 1) p += __shfl_xor(p, msk, 64);
        if (d == 0) srw[bh_ * SSZ + s] = p * scale;
    }
}

// ---------------------------------------------------------------------------
// Kernel 2: per (b,h): max, exp, inclusive cumsum -> Ep; per b: cumsum -> Pp.
// ---------------------------------------------------------------------------
__global__ __launch_bounds__(1024)
void scan_kernel(const float* __restrict__ srw, const float* __restrict__ gaps,
                 float* __restrict__ Ep, float* __restrict__ Pp)
{
    __shared__ float buf[SSZ];
    __shared__ float red[16];
    const int b = blockIdx.x >> 2, h = blockIdx.x & 3;
    const int tid = threadIdx.x;

    float v = srw[(b * HN + h) * SSZ + tid];
    float wm = v;
    #pragma unroll
    for (int msk = 32; msk >= 1; msk >>= 1) wm = fmaxf(wm, __shfl_xor(wm, msk, 64));
    if ((tid & 63) == 0) red[tid >> 6] = wm;
    __syncthreads();
    if (tid == 0) {
        float mm = red[0];
        for (int k = 1; k < 16; k++) mm = fmaxf(mm, red[k]);
        red[0] = mm;
    }
    __syncthreads();
    const float mx = red[0];

    float ex = __expf(v - mx);
    buf[tid] = ex;
    __syncthreads();
    for (int off = 1; off < SSZ; off <<= 1) {
        float tv = (tid >= off) ? buf[tid - off] : 0.0f;
        __syncthreads();
        buf[tid] += tv;
        __syncthreads();
    }
    Ep[(b * HN + h) * (SSZ + 1) + tid + 1] = buf[tid];
    if (tid == 0) Ep[(b * HN + h) * (SSZ + 1)] = 0.0f;

    if (h == 0) {
        float gv = fmaxf(gaps[b * SSZ + tid], 1.0f);
        __syncthreads();
        buf[tid] = gv;
        __syncthreads();
        for (int off = 1; off < SSZ; off <<= 1) {
            float tv = (tid >= off) ? buf[tid - off] : 0.0f;
            __syncthreads();
            buf[tid] += tv;
            __syncthreads();
        }
        Pp[b * (SSZ + 1) + tid + 1] = buf[tid];
        if (tid == 0) Pp[b * (SSZ + 1)] = 0.0f;
    }
}

// ---------------------------------------------------------------------------
// Kernel 3: attention. Block = (b, h, qtile of 64 queries); lane = query.
// 4 waves split key chunks round-robin; keys are wave-uniform (scalar loads).
// No max-subtraction (scores are tiny): partial states are pure sums.
// Writes normalized ctx to csw[row][h*32+d].
// ---------------------------------------------------------------------------
__global__ __launch_bounds__(256)
void attn2_kernel(const float* __restrict__ Qt, const float* __restrict__ Kt,
                  const float* __restrict__ Vt,
                  const float* __restrict__ Ep, const float* __restrict__ Pp,
                  const float* __restrict__ theta_raw, float* __restrict__ csw)
{
    __shared__ float part[4][64][33];
    const int bid = blockIdx.x;          // ((b*4+h)*16 + qt)
    const int qt = bid & 15;
    const int bh = bid >> 4;
    const int b = bh >> 2, h = bh & 3;
    const int tid = threadIdx.x;
    const int w = tid >> 6, lane = tid & 63;

    const int t = qt * 64 + 1 + lane;    // 1..1024 (1024 is invalid, masked at store)
    const int trow = (t <= 1023) ? t : 1023;

    const float theta = logf(1.0f + __expf(theta_raw[h])) + 1e-4f;
    const float nth = -theta;

    const float* Epb = Ep + bh * (SSZ + 1);
    const float* Ppb = Pp + b * (SSZ + 1);
    const float Ep_t = Epb[t];
    const float Pp_t = Ppb[t];
    const float inv_Ept = 1.0f / Ep_t;
    const float tf = (float)t;

    const float* Kb = Kt + (bh * SSZ) * DN;
    const float* Vb = Vt + (bh * SSZ) * DN;

    float q[DN];
    {
        const float scale = 0.17677669529663687f;
        const float* Qrow = Qt + (bh * SSZ + trow) * DN;
        #pragma unroll
        for (int d = 0; d < DN; d++) q[d] = Qrow[d] * scale;
    }

    float acc[DN];
    #pragma unroll
    for (int d = 0; d < DN; d++) acc[d] = 0.0f;
    float l = 0.0f;

    for (int c = w; c <= qt; c += 4) {
        const int i0 = c * 64;
        for (int ii = 0; ii < 64; ii++) {
            const int i = i0 + ii;
            const float4* Kr = (const float4*)(Kb + i * DN);
            float d0 = 0.f, d1 = 0.f, d2 = 0.f, d3 = 0.f;
            #pragma unroll
            for (int c8 = 0; c8 < 8; c8++) {
                const float4 kv = Kr[c8];
                d0 = fmaf(kv.x, q[4 * c8 + 0], d0);
                d1 = fmaf(kv.y, q[4 * c8 + 1], d1);
                d2 = fmaf(kv.z, q[4 * c8 + 2], d2);
                d3 = fmaf(kv.w, q[4 * c8 + 3], d3);
            }
            const float dot = (d0 + d1) + (d2 + d3);
            const float pdv = (tf - (float)i) * (Pp_t - Ppb[i]) * ((Ep_t - Epb[i]) * inv_Ept);
            const float decay = __expf(nth * pdv);
            const float sc = dot * decay;
            float p = __expf(sc);
            p = (i < t) ? p : 0.0f;
            l += p;
            const float4* Vr = (const float4*)(Vb + i * DN);
            #pragma unroll
            for (int c8 = 0; c8 < 8; c8++) {
                const float4 vv = Vr[c8];
                acc[4 * c8 + 0] = fmaf(p, vv.x, acc[4 * c8 + 0]);
                acc[4 * c8 + 1] = fmaf(p, vv.y, acc[4 * c8 + 1]);
                acc[4 * c8 + 2] = fmaf(p, vv.z, acc[4 * c8 + 2]);
                acc[4 * c8 + 3] = fmaf(p, vv.w, acc[4 * c8 + 3]);
            }
        }
    }

    #pragma unroll
    for (int d = 0; d < DN; d++) part[w][lane][d] = acc[d];
    part[w][lane][32] = l;
    __syncthreads();

    // 4-way sum merge + normalize + store ctx
    {
        const int qq = tid & 63, dg = tid >> 6;
        const int tq = qt * 64 + 1 + qq;
        if (tq <= 1023) {
            const float ls = part[0][qq][32] + part[1][qq][32]
                           + part[2][qq][32] + part[3][qq][32];
            const float inv = 1.0f / ls;
            float* dst = csw + (b * TQ + (tq - 1)) * EMBD + h * DN + dg * 8;
            #pragma unroll
            for (int d = 0; d < 8; d++) {
                const int dd = dg * 8 + d;
                const float s = part[0][qq][dd] + part[1][qq][dd]
                              + part[2][qq][dd] + part[3][qq][dd];
                dst[d] = s * inv;
            }
        }
    }
}

// ---------------------------------------------------------------------------
// Kernel 4: MLP. Block = 32 rows; thread tile = 2 rows x 8 cols.
// feat = [ctx(128); e(128)] staged in LDS. h1=relu(feat@W1+b1); logit=h1.W2+b2.
// ---------------------------------------------------------------------------
__global__ __launch_bounds__(256)
void mlp_kernel(const float* __restrict__ csw, const float* __restrict__ ec,
                const float* __restrict__ W1, const float* __restrict__ b1,
                const float* __restrict__ W2, const float* __restrict__ b2,
                float* __restrict__ out)
{
    __shared__ float feat[32][264];
    const int tid = threadIdx.x;
    const int r0 = blockIdx.x * 32;

    // stage 32 rows x 256 cols
    {
        const int rr = tid >> 3;             // 0..31
        const int cg = (tid & 7) * 32;       // 0,32,...,224
        const int row = r0 + rr;
        const int rowc = (row < NROWS) ? row : 0;
        const float4* src;
        if (cg < 128) {
            src = (const float4*)(csw + rowc * EMBD + cg);
        } else {
            const int bb = rowc / TQ;
            const int tt = rowc - bb * TQ + 1;
            src = (const float4*)(ec + (bb * SSZ + tt) * EMBD + (cg - 128));
        }
        #pragma unroll
        for (int k = 0; k < 8; k++) ((float4*)(&feat[rr][cg]))[k] = src[k];
    }
    __syncthreads();

    const int qp = tid >> 4;   // 0..15 -> rows qp*2, qp*2+1
    const int jg = tid & 15;   // cols jg*8..+8
    const int ra = qp * 2, rb = ra + 1;

    float a0[8], a1[8];
    #pragma unroll
    for (int j = 0; j < 8; j++) { a0[j] = 0.0f; a1[j] = 0.0f; }

    for (int i = 0; i < 256; i++) {
        const float f0 = feat[ra][i];
        const float f1 = feat[rb][i];
        const float4* wv = (const float4*)(W1 + i * EMBD + jg * 8);
        const float4 w0 = wv[0], w1 = wv[1];
        a0[0] = fmaf(f0, w0.x, a0[0]); a1[0] = fmaf(f1, w0.x, a1[0]);
        a0[1] = fmaf(f0, w0.y, a0[1]); a1[1] = fmaf(f1, w0.y, a1[1]);
        a0[2] = fmaf(f0, w0.z, a0[2]); a1[2] = fmaf(f1, w0.z, a1[2]);
        a0[3] = fmaf(f0, w0.w, a0[3]); a1[3] = fmaf(f1, w0.w, a1[3]);
        a0[4] = fmaf(f0, w1.x, a0[4]); a1[4] = fmaf(f1, w1.x, a1[4]);
        a0[5] = fmaf(f0, w1.y, a0[5]); a1[5] = fmaf(f1, w1.y, a1[5]);
        a0[6] = fmaf(f0, w1.z, a0[6]); a1[6] = fmaf(f1, w1.z, a1[6]);
        a0[7] = fmaf(f0, w1.w, a0[7]); a1[7] = fmaf(f1, w1.w, a1[7]);
    }

    const float4* b1v = (const float4*)(b1 + jg * 8);
    const float4* w2v = (const float4*)(W2 + jg * 8);
    const float4 bb0 = b1v[0], bb1 = b1v[1];
    const float4 ww0 = w2v[0], ww1 = w2v[1];
    float s0, s1;
    s0  = fmaxf(a0[0] + bb0.x, 0.0f) * ww0.x;  s1  = fmaxf(a1[0] + bb0.x, 0.0f) * ww0.x;
    s0 += fmaxf(a0[1] + bb0.y, 0.0f) * ww0.y;  s1 += fmaxf(a1[1] + bb0.y, 0.0f) * ww0.y;
    s0 += fmaxf(a0[2] + bb0.z, 0.0f) * ww0.z;  s1 += fmaxf(a1[2] + bb0.z, 0.0f) * ww0.z;
    s0 += fmaxf(a0[3] + bb0.w, 0.0f) * ww0.w;  s1 += fmaxf(a1[3] + bb0.w, 0.0f) * ww0.w;
    s0 += fmaxf(a0[4] + bb1.x, 0.0f) * ww1.x;  s1 += fmaxf(a1[4] + bb1.x, 0.0f) * ww1.x;
    s0 += fmaxf(a0[5] + bb1.y, 0.0f) * ww1.y;  s1 += fmaxf(a1[5] + bb1.y, 0.0f) * ww1.y;
    s0 += fmaxf(a0[6] + bb1.z, 0.0f) * ww1.z;  s1 += fmaxf(a1[6] + bb1.z, 0.0f) * ww1.z;
    s0 += fmaxf(a0[7] + bb1.w, 0.0f) * ww1.w;  s1 += fmaxf(a1[7] + bb1.w, 0.0f) * ww1.w;

    #pragma unroll
    for (int msk = 8; msk >= 1; msk >>= 1) {
        s0 += __shfl_xor(s0, msk, 64);
        s1 += __shfl_xor(s1, msk, 64);
    }
    if (jg == 0) {
        const float bias2 = b2[0];
        int row = r0 + ra;
        if (row < NROWS) {
            out[row] = 1.0f / (1.0f + __expf(-(s0 + bias2)));
            out[NROWS + row] = 1.0f;
        }
        row = r0 + rb;
        if (row < NROWS) {
            out[row] = 1.0f / (1.0f + __expf(-(s1 + bias2)));
            out[NROWS + row] = 1.0f;
        }
    }
}

// ---------------------------------------------------------------------------
extern "C" void kernel_launch(void* const* d_in, const int* in_sizes, int n_in,
                              void* d_out, int out_size, void* d_ws, size_t ws_size,
                              hipStream_t stream)
{
    const int*   idx       = (const int*)d_in[0];
    const int*   flg       = (const int*)d_in[1];
    const float* gaps      = (const float*)d_in[2];
    const float* item_emb  = (const float*)d_in[3];
    const float* ans_emb   = (const float*)d_in[4];
    const float* Wq        = (const float*)d_in[5];
    const float* bq        = (const float*)d_in[6];
    const float* Wk        = (const float*)d_in[7];
    const float* bk        = (const float*)d_in[8];
    const float* Wv        = (const float*)d_in[9];
    const float* bv        = (const float*)d_in[10];
    const float* Wh        = (const float*)d_in[11];
    const float* bh        = (const float*)d_in[12];
    const float* W1        = (const float*)d_in[13];
    const float* b1        = (const float*)d_in[14];
    const float* W2        = (const float*)d_in[15];
    const float* b2        = (const float*)d_in[16];
    const float* theta_raw = (const float*)d_in[17];

    float* ws  = (float*)d_ws;
    float* Qt  = ws;                           // 4*4*1024*32 = 524288
    float* Kt  = Qt + BSZ * HN * SSZ * DN;
    float* Vt  = Kt + BSZ * HN * SSZ * DN;
    float* ec  = Vt + BSZ * HN * SSZ * DN;     // 4*1024*128 = 524288
    float* srw = ec + BSZ * SSZ * EMBD;        // 16384
    float* Ep  = srw + BSZ * HN * SSZ;         // 16*1025 = 16400 (pad 16416)
    float* Pp  = Ep + 16416;                   // 4*1025 = 4100 (pad 4128)
    float* csw = Pp + 4128;                    // 4096*128 = 524288

    float* out = (float*)d_out;

    embed2_kernel<<<BSZ * SSZ / TT, 256, 0, stream>>>(
        idx, flg, item_emb, ans_emb, Wq, bq, Wk, bk, Wv, bv, Wh, bh,
        Qt, Kt, Vt, ec, srw);
    scan_kernel<<<BSZ * HN, 1024, 0, stream>>>(srw, gaps, Ep, Pp);
    attn2_kernel<<<BSZ * HN * 16, 256, 0, stream>>>(
        Qt, Kt, Vt, Ep, Pp, theta_raw, csw);
    mlp_kernel<<<(NROWS + 31) / 32, 256, 0, stream>>>(
        csw, ec, W1, b1, W2, b2, out);
}

// Round 4
// 307.627 us; speedup vs baseline: 2.0757x; 1.8227x over previous
//
#include <hip/hip_runtime.h>
#include <math.h>

#define BSZ 4
#define SSZ 1024
#define EMBD 128
#define HN 4
#define DN 32
#define TQ (SSZ - 1)      // 1023 queries per batch
#define NROWS (BSZ * TQ)  // 4092
#define CSW_FLOATS ((size_t)4096 * 128)   // csw region padded

// ---------------------------------------------------------------------------
// Kernel 1: embed + project. 16 tokens per block, 256 threads.
// ---------------------------------------------------------------------------
#define TT 16
__global__ __launch_bounds__(256)
void embed2_kernel(const int* __restrict__ idx, const int* __restrict__ flg,
                   const float* __restrict__ item_emb, const float* __restrict__ ans_emb,
                   const float* __restrict__ Wq, const float* __restrict__ bq,
                   const float* __restrict__ Wk, const float* __restrict__ bk,
                   const float* __restrict__ Wv, const float* __restrict__ bv,
                   const float* __restrict__ Wh, const float* __restrict__ bh,
                   float* __restrict__ Qt, float* __restrict__ Kt, float* __restrict__ Vt,
                   float* __restrict__ ec, float* __restrict__ srw)
{
    __shared__ float es[TT][132], as2[TT][132], inters[TT][132];
    const int tid = threadIdx.x;
    const int tok0 = blockIdx.x * TT;

    #pragma unroll
    for (int r = 0; r < 2; r++) {
        const int tk = r * 8 + (tid >> 5);
        const int v4 = tid & 31;
        const int tok = tok0 + tk;
        const float4 ev = ((const float4*)(item_emb + idx[tok] * EMBD))[v4];
        const float4 av = ((const float4*)(ans_emb  + flg[tok] * EMBD))[v4];
        *((float4*)(&es[tk][v4 * 4]))  = ev;
        *((float4*)(&as2[tk][v4 * 4])) = av;
        *((float4*)(ec + tok * EMBD + v4 * 4)) = ev;
    }
    __syncthreads();

    const int j  = tid & 127;
    const int hf = tid >> 7;
    const int T0 = hf * 8;

    float aI[8];
    {
        const float bhj = bh[j];
        #pragma unroll
        for (int k = 0; k < 8; k++) aI[k] = bhj;
    }
    for (int i = 0; i < 128; i++) {
        const float w = Wh[i * EMBD + j];
        #pragma unroll
        for (int k = 0; k < 8; k++) aI[k] = fmaf(es[T0 + k][i], w, aI[k]);
    }
    for (int i = 0; i < 128; i++) {
        const float w = Wh[(128 + i) * EMBD + j];
        #pragma unroll
        for (int k = 0; k < 8; k++) aI[k] = fmaf(as2[T0 + k][i], w, aI[k]);
    }

    float aQ[8], aK[8];
    {
        const float bqj = bq[j], bkj = bk[j];
        #pragma unroll
        for (int k = 0; k < 8; k++) { aQ[k] = bqj; aK[k] = bkj; }
    }
    for (int i = 0; i < 128; i++) {
        const float wq = Wq[i * EMBD + j];
        const float wk = Wk[i * EMBD + j];
        #pragma unroll
        for (int k = 0; k < 8; k++) {
            const float e = es[T0 + k][i];
            aQ[k] = fmaf(e, wq, aQ[k]);
            aK[k] = fmaf(e, wk, aK[k]);
        }
    }

    #pragma unroll
    for (int k = 0; k < 8; k++) inters[T0 + k][j] = aI[k];
    __syncthreads();

    float aV[8];
    {
        const float bvj = bv[j];
        #pragma unroll
        for (int k = 0; k < 8; k++) aV[k] = bvj;
    }
    for (int i = 0; i < 128; i++) {
        const float w = Wv[i * EMBD + j];
        #pragma unroll
        for (int k = 0; k < 8; k++) aV[k] = fmaf(inters[T0 + k][i], w, aV[k]);
    }

    const int b = tok0 >> 10;
    const int h = j >> 5, d = j & 31;
    const int bh_ = b * HN + h;
    const float scale = 0.17677669529663687f;
    #pragma unroll
    for (int k = 0; k < 8; k++) {
        const int s = (tok0 & 1023) + T0 + k;
        const int qi = (bh_ * SSZ + s) * DN + d;
        Qt[qi] = aQ[k]; Kt[qi] = aK[k]; Vt[qi] = aV[k];
        float p = aQ[k] * aK[k];
        #pragma unroll
        for (int msk = 16; msk >= 1; msk >>= 1) p += __shfl_xor(p, msk, 64);
        if (d == 0) srw[bh_ * SSZ + s] = p * scale;
    }
}

// ---------------------------------------------------------------------------
// Kernel 2: scans -> Ep, Pp.
// ---------------------------------------------------------------------------
__global__ __launch_bounds__(1024)
void scan_kernel(const float* __restrict__ srw, const float* __restrict__ gaps,
                 float* __restrict__ Ep, float* __restrict__ Pp)
{
    __shared__ float buf[SSZ];
    __shared__ float red[16];
    const int b = blockIdx.x >> 2, h = blockIdx.x & 3;
    const int tid = threadIdx.x;

    float v = srw[(b * HN + h) * SSZ + tid];
    float wm = v;
    #pragma unroll
    for (int msk = 32; msk >= 1; msk >>= 1) wm = fmaxf(wm, __shfl_xor(wm, msk, 64));
    if ((tid & 63) == 0) red[tid >> 6] = wm;
    __syncthreads();
    if (tid == 0) {
        float mm = red[0];
        for (int k = 1; k < 16; k++) mm = fmaxf(mm, red[k]);
        red[0] = mm;
    }
    __syncthreads();
    const float mx = red[0];

    float ex = __expf(v - mx);
    buf[tid] = ex;
    __syncthreads();
    for (int off = 1; off < SSZ; off <<= 1) {
        float tv = (tid >= off) ? buf[tid - off] : 0.0f;
        __syncthreads();
        buf[tid] += tv;
        __syncthreads();
    }
    Ep[(b * HN + h) * (SSZ + 1) + tid + 1] = buf[tid];
    if (tid == 0) Ep[(b * HN + h) * (SSZ + 1)] = 0.0f;

    if (h == 0) {
        float gv = fmaxf(gaps[b * SSZ + tid], 1.0f);
        __syncthreads();
        buf[tid] = gv;
        __syncthreads();
        for (int off = 1; off < SSZ; off <<= 1) {
            float tv = (tid >= off) ? buf[tid - off] : 0.0f;
            __syncthreads();
            buf[tid] += tv;
            __syncthreads();
        }
        Pp[b * (SSZ + 1) + tid + 1] = buf[tid];
        if (tid == 0) Pp[b * (SSZ + 1)] = 0.0f;
    }
}

// ---------------------------------------------------------------------------
// Kernel 3: attention partials. Block = (bh, qt, slice s in [0,4)).
// Wave w handles key chunk c = s + 4*w (64 keys) iff c <= qt, else zeros.
// Lane = query (t = qt*64+1+lane). In-block 4-wave sum-merge -> psum (raw,
// unnormalized): psum[((bh*16+qt)*4+s)*64 + q][36]  (d 0..31, l at 32).
// ---------------------------------------------------------------------------
__global__ __launch_bounds__(256)
void attn3_kernel(const float* __restrict__ Qt, const float* __restrict__ Kt,
                  const float* __restrict__ Vt,
                  const float* __restrict__ Ep, const float* __restrict__ Pp,
                  const float* __restrict__ theta_raw, float* __restrict__ psum)
{
    __shared__ float part[4][64][33];
    const int bid = blockIdx.x;
    const int s  = bid & 3;
    const int qt = (bid >> 2) & 15;
    const int bh = bid >> 6;
    const int b  = bh >> 2, h = bh & 3;
    const int tid = threadIdx.x;
    const int w = tid >> 6, lane = tid & 63;

    const int t = qt * 64 + 1 + lane;
    const int trow = (t <= 1023) ? t : 1023;
    const int c = s + 4 * w;
    const bool active = (c <= qt);

    float acc[DN];
    #pragma unroll
    for (int d = 0; d < DN; d++) acc[d] = 0.0f;
    float l = 0.0f;

    if (active) {
        const float theta = logf(1.0f + __expf(theta_raw[h])) + 1e-4f;
        const float nth = -theta;
        const float* Epb = Ep + bh * (SSZ + 1);
        const float* Ppb = Pp + b * (SSZ + 1);
        const float Ep_t = Epb[t];
        const float Pp_t = Ppb[t];
        const float inv_Ept = 1.0f / Ep_t;
        const float tf = (float)t;
        const float* Kb = Kt + (bh * SSZ) * DN;
        const float* Vb = Vt + (bh * SSZ) * DN;

        float q[DN];
        {
            const float scale = 0.17677669529663687f;
            const float* Qrow = Qt + (bh * SSZ + trow) * DN;
            #pragma unroll
            for (int d = 0; d < DN; d++) q[d] = Qrow[d] * scale;
        }

        const int i0 = c * 64;
        #pragma unroll 2
        for (int ii = 0; ii < 64; ii++) {
            const int i = i0 + ii;
            const float4* Kr = (const float4*)(Kb + i * DN);
            float d0 = 0.f, d1 = 0.f, d2 = 0.f, d3 = 0.f;
            #pragma unroll
            for (int c8 = 0; c8 < 8; c8++) {
                const float4 kv = Kr[c8];
                d0 = fmaf(kv.x, q[4 * c8 + 0], d0);
                d1 = fmaf(kv.y, q[4 * c8 + 1], d1);
                d2 = fmaf(kv.z, q[4 * c8 + 2], d2);
                d3 = fmaf(kv.w, q[4 * c8 + 3], d3);
            }
            const float dot = (d0 + d1) + (d2 + d3);
            const float pdv = (tf - (float)i) * (Pp_t - Ppb[i]) * ((Ep_t - Epb[i]) * inv_Ept);
            const float sc = dot * __expf(nth * pdv);
            float p = __expf(sc);
            p = (i < t) ? p : 0.0f;
            l += p;
            const float4* Vr = (const float4*)(Vb + i * DN);
            #pragma unroll
            for (int c8 = 0; c8 < 8; c8++) {
                const float4 vv = Vr[c8];
                acc[4 * c8 + 0] = fmaf(p, vv.x, acc[4 * c8 + 0]);
                acc[4 * c8 + 1] = fmaf(p, vv.y, acc[4 * c8 + 1]);
                acc[4 * c8 + 2] = fmaf(p, vv.z, acc[4 * c8 + 2]);
                acc[4 * c8 + 3] = fmaf(p, vv.w, acc[4 * c8 + 3]);
            }
        }
    }

    #pragma unroll
    for (int d = 0; d < DN; d++) part[w][lane][d] = acc[d];
    part[w][lane][32] = l;
    __syncthreads();

    // merge 4 waves, store raw partial
    {
        const int qq = tid & 63, dg = tid >> 6;
        float* dst = psum + (size_t)(bid * 64 + qq) * 36;
        #pragma unroll
        for (int d = 0; d < 8; d++) {
            const int dd = dg * 8 + d;
            dst[dd] = part[0][qq][dd] + part[1][qq][dd]
                    + part[2][qq][dd] + part[3][qq][dd];
        }
        if (dg == 0)
            dst[32] = part[0][qq][32] + part[1][qq][32]
                    + part[2][qq][32] + part[3][qq][32];
    }
}

// ---------------------------------------------------------------------------
// Kernel 3b: merge 4 slices, normalize, write csw[row][h*32+d].
// Block = (bh, qt), 256 threads: q = tid>>2, dg = tid&3 (8 d's each).
// ---------------------------------------------------------------------------
__global__ __launch_bounds__(256)
void attn_merge_kernel(const float* __restrict__ psum, float* __restrict__ csw)
{
    const int bid = blockIdx.x;        // bh*16 + qt
    const int qt = bid & 15;
    const int bh = bid >> 4;
    const int b = bh >> 2, h = bh & 3;
    const int tid = threadIdx.x;
    const int q = tid >> 2, dg = tid & 3;

    const int tq = qt * 64 + 1 + q;
    if (tq > 1023) return;

    const float* base = psum + (size_t)(bid * 4) * 64 * 36 + q * 36;
    float v[8];
    #pragma unroll
    for (int d = 0; d < 8; d++) v[d] = 0.0f;
    float l = 0.0f;
    #pragma unroll
    for (int sl = 0; sl < 4; sl++) {
        const float* p = base + sl * 64 * 36;
        #pragma unroll
        for (int d = 0; d < 8; d++) v[d] += p[dg * 8 + d];
        l += p[32];
    }
    const float inv = 1.0f / l;
    float* dst = csw + (size_t)(b * TQ + (tq - 1)) * EMBD + h * DN + dg * 8;
    #pragma unroll
    for (int d = 0; d < 8; d++) dst[d] = v[d] * inv;
}

// ---------------------------------------------------------------------------
// Kernel 4: MLP. Block = 32 rows; thread tile = 2 rows x 8 cols.
// ---------------------------------------------------------------------------
__global__ __launch_bounds__(256)
void mlp_kernel(const float* __restrict__ csw, const float* __restrict__ ec,
                const float* __restrict__ W1, const float* __restrict__ b1,
                const float* __restrict__ W2, const float* __restrict__ b2,
                float* __restrict__ out)
{
    __shared__ float feat[32][264];
    const int tid = threadIdx.x;
    const int r0 = blockIdx.x * 32;

    {
        const int rr = tid >> 3;
        const int cg = (tid & 7) * 32;
        const int row = r0 + rr;
        const int rowc = (row < NROWS) ? row : 0;
        const float4* src;
        if (cg < 128) {
            src = (const float4*)(csw + rowc * EMBD + cg);
        } else {
            const int bb = rowc / TQ;
            const int tt = rowc - bb * TQ + 1;
            src = (const float4*)(ec + (bb * SSZ + tt) * EMBD + (cg - 128));
        }
        #pragma unroll
        for (int k = 0; k < 8; k++) ((float4*)(&feat[rr][cg]))[k] = src[k];
    }
    __syncthreads();

    const int qp = tid >> 4;
    const int jg = tid & 15;
    const int ra = qp * 2, rb = ra + 1;

    float a0[8], a1[8];
    #pragma unroll
    for (int j = 0; j < 8; j++) { a0[j] = 0.0f; a1[j] = 0.0f; }

    for (int i = 0; i < 256; i++) {
        const float f0 = feat[ra][i];
        const float f1 = feat[rb][i];
        const float4* wv = (const float4*)(W1 + i * EMBD + jg * 8);
        const float4 w0 = wv[0], w1 = wv[1];
        a0[0] = fmaf(f0, w0.x, a0[0]); a1[0] = fmaf(f1, w0.x, a1[0]);
        a0[1] = fmaf(f0, w0.y, a0[1]); a1[1] = fmaf(f1, w0.y, a1[1]);
        a0[2] = fmaf(f0, w0.z, a0[2]); a1[2] = fmaf(f1, w0.z, a1[2]);
        a0[3] = fmaf(f0, w0.w, a0[3]); a1[3] = fmaf(f1, w0.w, a1[3]);
        a0[4] = fmaf(f0, w1.x, a0[4]); a1[4] = fmaf(f1, w1.x, a1[4]);
        a0[5] = fmaf(f0, w1.y, a0[5]); a1[5] = fmaf(f1, w1.y, a1[5]);
        a0[6] = fmaf(f0, w1.z, a0[6]); a1[6] = fmaf(f1, w1.z, a1[6]);
        a0[7] = fmaf(f0, w1.w, a0[7]); a1[7] = fmaf(f1, w1.w, a1[7]);
    }

    const float4* b1v = (const float4*)(b1 + jg * 8);
    const float4* w2v = (const float4*)(W2 + jg * 8);
    const float4 bb0 = b1v[0], bb1 = b1v[1];
    const float4 ww0 = w2v[0], ww1 = w2v[1];
    float s0, s1;
    s0  = fmaxf(a0[0] + bb0.x, 0.0f) * ww0.x;  s1  = fmaxf(a1[0] + bb0.x, 0.0f) * ww0.x;
    s0 += fmaxf(a0[1] + bb0.y, 0.0f) * ww0.y;  s1 += fmaxf(a1[1] + bb0.y, 0.0f) * ww0.y;
    s0 += fmaxf(a0[2] + bb0.z, 0.0f) * ww0.z;  s1 += fmaxf(a1[2] + bb0.z, 0.0f) * ww0.z;
    s0 += fmaxf(a0[3] + bb0.w, 0.0f) * ww0.w;  s1 += fmaxf(a1[3] + bb0.w, 0.0f) * ww0.w;
    s0 += fmaxf(a0[4] + bb1.x, 0.0f) * ww1.x;  s1 += fmaxf(a1[4] + bb1.x, 0.0f) * ww1.x;
    s0 += fmaxf(a0[5] + bb1.y, 0.0f) * ww1.y;  s1 += fmaxf(a1[5] + bb1.y, 0.0f) * ww1.y;
    s0 += fmaxf(a0[6] + bb1.z, 0.0f) * ww1.z;  s1 += fmaxf(a1[6] + bb1.z, 0.0f) * ww1.z;
    s0 += fmaxf(a0[7] + bb1.w, 0.0f) * ww1.w;  s1 += fmaxf(a1[7] + bb1.w, 0.0f) * ww1.w;

    #pragma unroll
    for (int msk = 8; msk >= 1; msk >>= 1) {
        s0 += __shfl_xor(s0, msk, 64);
        s1 += __shfl_xor(s1, msk, 64);
    }
    if (jg == 0) {
        const float bias2 = b2[0];
        int row = r0 + ra;
        if (row < NROWS) {
            out[row] = 1.0f / (1.0f + __expf(-(s0 + bias2)));
            out[NROWS + row] = 1.0f;
        }
        row = r0 + rb;
        if (row < NROWS) {
            out[row] = 1.0f / (1.0f + __expf(-(s1 + bias2)));
            out[NROWS + row] = 1.0f;
        }
    }
}

// ---------------------------------------------------------------------------
extern "C" void kernel_launch(void* const* d_in, const int* in_sizes, int n_in,
                              void* d_out, int out_size, void* d_ws, size_t ws_size,
                              hipStream_t stream)
{
    const int*   idx       = (const int*)d_in[0];
    const int*   flg       = (const int*)d_in[1];
    const float* gaps      = (const float*)d_in[2];
    const float* item_emb  = (const float*)d_in[3];
    const float* ans_emb   = (const float*)d_in[4];
    const float* Wq        = (const float*)d_in[5];
    const float* bq        = (const float*)d_in[6];
    const float* Wk        = (const float*)d_in[7];
    const float* bk        = (const float*)d_in[8];
    const float* Wv        = (const float*)d_in[9];
    const float* bv        = (const float*)d_in[10];
    const float* Wh        = (const float*)d_in[11];
    const float* bh        = (const float*)d_in[12];
    const float* W1        = (const float*)d_in[13];
    const float* b1        = (const float*)d_in[14];
    const float* W2        = (const float*)d_in[15];
    const float* b2        = (const float*)d_in[16];
    const float* theta_raw = (const float*)d_in[17];

    float* ws  = (float*)d_ws;
    float* Qt  = ws;                           // 524288
    float* Kt  = Qt + BSZ * HN * SSZ * DN;     // 524288
    float* Vt  = Kt + BSZ * HN * SSZ * DN;     // 524288
    float* ec  = Vt + BSZ * HN * SSZ * DN;     // 524288
    float* srw = ec + BSZ * SSZ * EMBD;        // 16384
    float* Ep  = srw + BSZ * HN * SSZ;         // 16416
    float* Pp  = Ep + 16416;                   // 4128
    float* csw = Pp + 4128;                    // CSW_FLOATS
    float* psum = csw + CSW_FLOATS;            // 4096 blocks * 64 q * 36 = 9.4M floats
    (void)ws_size;

    float* out = (float*)d_out;

    embed2_kernel<<<BSZ * SSZ / TT, 256, 0, stream>>>(
        idx, flg, item_emb, ans_emb, Wq, bq, Wk, bk, Wv, bv, Wh, bh,
        Qt, Kt, Vt, ec, srw);
    scan_kernel<<<BSZ * HN, 1024, 0, stream>>>(srw, gaps, Ep, Pp);
    attn3_kernel<<<BSZ * HN * 16 * 4, 256, 0, stream>>>(
        Qt, Kt, Vt, Ep, Pp, theta_raw, psum);
    attn_merge_kernel<<<BSZ * HN * 16, 256, 0, stream>>>(psum, csw);
    mlp_kernel<<<(NROWS + 31) / 32, 256, 0, stream>>>(
        csw, ec, W1, b1, W2, b2, out);
}

// Round 5
// 201.027 us; speedup vs baseline: 3.1764x; 1.5303x over previous
//
#include <hip/hip_runtime.h>
#include <math.h>

#define BSZ 4
#define SSZ 1024
#define EMBD 128
#define HN 4
#define DN 32
#define TQ (SSZ - 1)      // 1023 queries per batch
#define NROWS (BSZ * TQ)  // 4092

typedef __attribute__((ext_vector_type(8))) short bf16x8;
typedef __attribute__((ext_vector_type(4))) float f32x4;

static __device__ __forceinline__ unsigned short f2bf(float x) {
    union { float f; unsigned u; } v; v.f = x;
    unsigned r = v.u + 0x7fffu + ((v.u >> 16) & 1u);   // RNE
    return (unsigned short)(r >> 16);
}

// ---------------------------------------------------------------------------
// Kernel 1: embed + project. 16 tokens per block, 256 threads. (unchanged)
// ---------------------------------------------------------------------------
#define TT 16
__global__ __launch_bounds__(256)
void embed2_kernel(const int* __restrict__ idx, const int* __restrict__ flg,
                   const float* __restrict__ item_emb, const float* __restrict__ ans_emb,
                   const float* __restrict__ Wq, const float* __restrict__ bq,
                   const float* __restrict__ Wk, const float* __restrict__ bk,
                   const float* __restrict__ Wv, const float* __restrict__ bv,
                   const float* __restrict__ Wh, const float* __restrict__ bh,
                   float* __restrict__ Qt, float* __restrict__ Kt, float* __restrict__ Vt,
                   float* __restrict__ ec, float* __restrict__ srw)
{
    __shared__ float es[TT][132], as2[TT][132], inters[TT][132];
    const int tid = threadIdx.x;
    const int tok0 = blockIdx.x * TT;

    #pragma unroll
    for (int r = 0; r < 2; r++) {
        const int tk = r * 8 + (tid >> 5);
        const int v4 = tid & 31;
        const int tok = tok0 + tk;
        const float4 ev = ((const float4*)(item_emb + idx[tok] * EMBD))[v4];
        const float4 av = ((const float4*)(ans_emb  + flg[tok] * EMBD))[v4];
        *((float4*)(&es[tk][v4 * 4]))  = ev;
        *((float4*)(&as2[tk][v4 * 4])) = av;
        *((float4*)(ec + tok * EMBD + v4 * 4)) = ev;
    }
    __syncthreads();

    const int j  = tid & 127;
    const int hf = tid >> 7;
    const int T0 = hf * 8;

    float aI[8];
    {
        const float bhj = bh[j];
        #pragma unroll
        for (int k = 0; k < 8; k++) aI[k] = bhj;
    }
    for (int i = 0; i < 128; i++) {
        const float w = Wh[i * EMBD + j];
        #pragma unroll
        for (int k = 0; k < 8; k++) aI[k] = fmaf(es[T0 + k][i], w, aI[k]);
    }
    for (int i = 0; i < 128; i++) {
        const float w = Wh[(128 + i) * EMBD + j];
        #pragma unroll
        for (int k = 0; k < 8; k++) aI[k] = fmaf(as2[T0 + k][i], w, aI[k]);
    }

    float aQ[8], aK[8];
    {
        const float bqj = bq[j], bkj = bk[j];
        #pragma unroll
        for (int k = 0; k < 8; k++) { aQ[k] = bqj; aK[k] = bkj; }
    }
    for (int i = 0; i < 128; i++) {
        const float wq = Wq[i * EMBD + j];
        const float wk = Wk[i * EMBD + j];
        #pragma unroll
        for (int k = 0; k < 8; k++) {
            const float e = es[T0 + k][i];
            aQ[k] = fmaf(e, wq, aQ[k]);
            aK[k] = fmaf(e, wk, aK[k]);
        }
    }

    #pragma unroll
    for (int k = 0; k < 8; k++) inters[T0 + k][j] = aI[k];
    __syncthreads();

    float aV[8];
    {
        const float bvj = bv[j];
        #pragma unroll
        for (int k = 0; k < 8; k++) aV[k] = bvj;
    }
    for (int i = 0; i < 128; i++) {
        const float w = Wv[i * EMBD + j];
        #pragma unroll
        for (int k = 0; k < 8; k++) aV[k] = fmaf(inters[T0 + k][i], w, aV[k]);
    }

    const int b = tok0 >> 10;
    const int h = j >> 5, d = j & 31;
    const int bh_ = b * HN + h;
    const float scale = 0.17677669529663687f;
    #pragma unroll
    for (int k = 0; k < 8; k++) {
        const int s = (tok0 & 1023) + T0 + k;
        const int qi = (bh_ * SSZ + s) * DN + d;
        Qt[qi] = aQ[k]; Kt[qi] = aK[k]; Vt[qi] = aV[k];
        float p = aQ[k] * aK[k];
        #pragma unroll
        for (int msk = 16; msk >= 1; msk >>= 1) p += __shfl_xor(p, msk, 64);
        if (d == 0) srw[bh_ * SSZ + s] = p * scale;
    }
}

// ---------------------------------------------------------------------------
// Kernel 2: scans. Blocks 0..15: Ep for bh. Blocks 16..19: Pp for b.
// ---------------------------------------------------------------------------
__global__ __launch_bounds__(1024)
void scan_kernel(const float* __restrict__ srw, const float* __restrict__ gaps,
                 float* __restrict__ Ep, float* __restrict__ Pp)
{
    __shared__ float buf[SSZ];
    __shared__ float red[16];
    const int tid = threadIdx.x;

    if (blockIdx.x < 16) {
        const int bh = blockIdx.x;
        float v = srw[bh * SSZ + tid];
        float wm = v;
        #pragma unroll
        for (int msk = 32; msk >= 1; msk >>= 1) wm = fmaxf(wm, __shfl_xor(wm, msk, 64));
        if ((tid & 63) == 0) red[tid >> 6] = wm;
        __syncthreads();
        if (tid == 0) {
            float mm = red[0];
            for (int k = 1; k < 16; k++) mm = fmaxf(mm, red[k]);
            red[0] = mm;
        }
        __syncthreads();
        const float mx = red[0];

        buf[tid] = __expf(v - mx);
        __syncthreads();
        for (int off = 1; off < SSZ; off <<= 1) {
            float tv = (tid >= off) ? buf[tid - off] : 0.0f;
            __syncthreads();
            buf[tid] += tv;
            __syncthreads();
        }
        Ep[bh * (SSZ + 1) + tid + 1] = buf[tid];
        if (tid == 0) Ep[bh * (SSZ + 1)] = 0.0f;
    } else {
        const int b = blockIdx.x - 16;
        buf[tid] = fmaxf(gaps[b * SSZ + tid], 1.0f);
        __syncthreads();
        for (int off = 1; off < SSZ; off <<= 1) {
            float tv = (tid >= off) ? buf[tid - off] : 0.0f;
            __syncthreads();
            buf[tid] += tv;
            __syncthreads();
        }
        Pp[b * (SSZ + 1) + tid + 1] = buf[tid];
        if (tid == 0) Pp[b * (SSZ + 1)] = 0.0f;
    }
}

// ---------------------------------------------------------------------------
// Kernel 3: MFMA attention. Block = (bh, qtile of 64 queries). 4 waves.
// Wave w owns queries qq in [16w,16w+16). Loop over 64-key chunks:
//   stage K,V (bf16) + compute QK^T (4 mfma) -> decay/exp -> P to LDS ->
//   PV (4 mfma into persistent acc). Normalize + write csw at end.
// Layouts (verified gfx950): A[m=lane&15][k=quad*8+j], B[n=lane&15][k=quad*8+j],
// C/D: row=quad*4+reg, col=lane&15.
// ---------------------------------------------------------------------------
__global__ __launch_bounds__(256)
void attn_mfma_kernel(const float* __restrict__ Qt, const float* __restrict__ Kt,
                      const float* __restrict__ Vt,
                      const float* __restrict__ Ep, const float* __restrict__ Pp,
                      const float* __restrict__ theta_raw, float* __restrict__ csw)
{
    __shared__ __align__(16) unsigned short Qs[64][40];   // [qq][d], pad->80B rows
    __shared__ __align__(16) unsigned short Ks[64][40];   // [i_local][d]
    __shared__ __align__(16) unsigned short Vs[32][72];   // [d][i_local], pad->144B rows
    __shared__ __align__(16) unsigned short Ps[4][16][72];// per-wave [m][i_local]
    __shared__ float EpS[SSZ + 1];
    __shared__ float PpS[SSZ + 1];

    const int bid = blockIdx.x;        // bh*16 + qt
    const int qt = bid & 15;
    const int bh = bid >> 4;
    const int b = bh >> 2, h = bh & 3;
    const int tid = threadIdx.x;
    const int w = tid >> 6, lane = tid & 63;
    const int quad = lane >> 4, col = lane & 15;
    const int t0 = qt * 64 + 1;
    const float scale = 0.17677669529663687f;

    // ---- stage Ep/Pp (full 1025 each) ----
    {
        const float* Epb = Ep + bh * (SSZ + 1);
        const float* Ppb = Pp + b * (SSZ + 1);
        for (int x = tid; x <= SSZ; x += 256) { EpS[x] = Epb[x]; PpS[x] = Ppb[x]; }
    }
    // ---- stage Q tile as bf16 (x scale), rows qq=0..63 -> t0+qq (clamped) ----
    {
        const int qq = tid >> 2;
        const int d0 = (tid & 3) * 8;
        int t = t0 + qq; if (t > 1023) t = 1023;
        const float* src = Qt + ((size_t)(bh * SSZ + t)) * DN + d0;
        bf16x8 v;
        #pragma unroll
        for (int k = 0; k < 8; k++) v[k] = (short)f2bf(src[k] * scale);
        *(bf16x8*)&Qs[qq][d0] = v;
    }
    __syncthreads();

    // per-lane loop invariants
    const float theta = logf(1.0f + __expf(theta_raw[h])) + 1e-4f;
    const float nth = -theta;
    float Ept[4], Ppt[4], iEp[4], tft[4];
    int qrow[4], tq[4];
    #pragma unroll
    for (int r = 0; r < 4; r++) {
        qrow[r] = w * 16 + quad * 4 + r;
        tq[r] = t0 + qrow[r];
        tft[r] = (float)tq[r];
        Ept[r] = EpS[tq[r]];
        Ppt[r] = PpS[tq[r]];
        iEp[r] = 1.0f / Ept[r];
    }

    const bf16x8 aq = *(const bf16x8*)&Qs[w * 16 + col][quad * 8];

    f32x4 acc0 = {0.f, 0.f, 0.f, 0.f};
    f32x4 acc1 = {0.f, 0.f, 0.f, 0.f};
    float lsum[4] = {0.f, 0.f, 0.f, 0.f};

    for (int c = 0; c <= qt; c++) {
        __syncthreads();   // previous chunk fully consumed
        // ---- stage K chunk [i][d] ----
        {
            const int i = tid >> 2;
            const int d0 = (tid & 3) * 8;
            const float* src = Kt + ((size_t)(bh * SSZ + c * 64 + i)) * DN + d0;
            bf16x8 v;
            #pragma unroll
            for (int k = 0; k < 8; k++) v[k] = (short)f2bf(src[k]);
            *(bf16x8*)&Ks[i][d0] = v;
        }
        // ---- stage V chunk transposed [d][i] ----
        {
            const int i = tid >> 2;
            const int d0 = (tid & 3) * 8;
            const float* src = Vt + ((size_t)(bh * SSZ + c * 64 + i)) * DN + d0;
            #pragma unroll
            for (int k = 0; k < 8; k++) Vs[d0 + k][i] = f2bf(src[k]);
        }
        __syncthreads();

        const bool full = (c < qt);
        // ---- QK^T + decay + P ----
        #pragma unroll
        for (int nt = 0; nt < 4; nt++) {
            const bf16x8 bk = *(const bf16x8*)&Ks[nt * 16 + col][quad * 8];
            f32x4 z = {0.f, 0.f, 0.f, 0.f};
            f32x4 raw = __builtin_amdgcn_mfma_f32_16x16x32_bf16(aq, bk, z, 0, 0, 0);
            const int il = nt * 16 + col;
            const int i_ = c * 64 + il;
            const float Epi = EpS[i_];
            const float Ppi = PpS[i_];
            const float fi = (float)i_;
            #pragma unroll
            for (int r = 0; r < 4; r++) {
                const float pdv = (tft[r] - fi) * (Ppt[r] - Ppi) * ((Ept[r] - Epi) * iEp[r]);
                const float sc  = raw[r] * __expf(nth * pdv);
                float p = __expf(sc);
                p = (full || il <= qrow[r]) ? p : 0.0f;
                lsum[r] += p;
                Ps[w][quad * 4 + r][il] = f2bf(p);
            }
        }
        // ---- PV (same wave wrote Ps; lgkmcnt handles ordering) ----
        #pragma unroll
        for (int ks = 0; ks < 2; ks++) {
            const bf16x8 ap = *(const bf16x8*)&Ps[w][col][ks * 32 + quad * 8];
            const bf16x8 bv0 = *(const bf16x8*)&Vs[col][ks * 32 + quad * 8];
            const bf16x8 bv1 = *(const bf16x8*)&Vs[16 + col][ks * 32 + quad * 8];
            acc0 = __builtin_amdgcn_mfma_f32_16x16x32_bf16(ap, bv0, acc0, 0, 0, 0);
            acc1 = __builtin_amdgcn_mfma_f32_16x16x32_bf16(ap, bv1, acc1, 0, 0, 0);
        }
    }

    // ---- row sums of l over the 16 lanes of each quad ----
    #pragma unroll
    for (int r = 0; r < 4; r++) {
        float lr = lsum[r];
        #pragma unroll
        for (int msk = 8; msk >= 1; msk >>= 1) lr += __shfl_xor(lr, msk, 64);
        lsum[r] = 1.0f / lr;
    }

    // ---- normalize + store ctx ----
    #pragma unroll
    for (int r = 0; r < 4; r++) {
        if (tq[r] <= 1023) {
            float* dst = csw + ((size_t)(b * TQ + (tq[r] - 1))) * EMBD + h * DN;
            dst[col]      = acc0[r] * lsum[r];
            dst[16 + col] = acc1[r] * lsum[r];
        }
    }
}

// ---------------------------------------------------------------------------
// Kernel 4: MLP. Block = 32 rows; thread tile = 2 rows x 8 cols. (unchanged)
// ---------------------------------------------------------------------------
__global__ __launch_bounds__(256)
void mlp_kernel(const float* __restrict__ csw, const float* __restrict__ ec,
                const float* __restrict__ W1, const float* __restrict__ b1,
                const float* __restrict__ W2, const float* __restrict__ b2,
                float* __restrict__ out)
{
    __shared__ float feat[32][264];
    const int tid = threadIdx.x;
    const int r0 = blockIdx.x * 32;

    {
        const int rr = tid >> 3;
        const int cg = (tid & 7) * 32;
        const int row = r0 + rr;
        const int rowc = (row < NROWS) ? row : 0;
        const float4* src;
        if (cg < 128) {
            src = (const float4*)(csw + rowc * EMBD + cg);
        } else {
            const int bb = rowc / TQ;
            const int tt = rowc - bb * TQ + 1;
            src = (const float4*)(ec + (bb * SSZ + tt) * EMBD + (cg - 128));
        }
        #pragma unroll
        for (int k = 0; k < 8; k++) ((float4*)(&feat[rr][cg]))[k] = src[k];
    }
    __syncthreads();

    const int qp = tid >> 4;
    const int jg = tid & 15;
    const int ra = qp * 2, rb = ra + 1;

    float a0[8], a1[8];
    #pragma unroll
    for (int j = 0; j < 8; j++) { a0[j] = 0.0f; a1[j] = 0.0f; }

    for (int i = 0; i < 256; i++) {
        const float f0 = feat[ra][i];
        const float f1 = feat[rb][i];
        const float4* wv = (const float4*)(W1 + i * EMBD + jg * 8);
        const float4 w0 = wv[0], w1 = wv[1];
        a0[0] = fmaf(f0, w0.x, a0[0]); a1[0] = fmaf(f1, w0.x, a1[0]);
        a0[1] = fmaf(f0, w0.y, a0[1]); a1[1] = fmaf(f1, w0.y, a1[1]);
        a0[2] = fmaf(f0, w0.z, a0[2]); a1[2] = fmaf(f1, w0.z, a1[2]);
        a0[3] = fmaf(f0, w0.w, a0[3]); a1[3] = fmaf(f1, w0.w, a1[3]);
        a0[4] = fmaf(f0, w1.x, a0[4]); a1[4] = fmaf(f1, w1.x, a1[4]);
        a0[5] = fmaf(f0, w1.y, a0[5]); a1[5] = fmaf(f1, w1.y, a1[5]);
        a0[6] = fmaf(f0, w1.z, a0[6]); a1[6] = fmaf(f1, w1.z, a1[6]);
        a0[7] = fmaf(f0, w1.w, a0[7]); a1[7] = fmaf(f1, w1.w, a1[7]);
    }

    const float4* b1v = (const float4*)(b1 + jg * 8);
    const float4* w2v = (const float4*)(W2 + jg * 8);
    const float4 bb0 = b1v[0], bb1 = b1v[1];
    const float4 ww0 = w2v[0], ww1 = w2v[1];
    float s0, s1;
    s0  = fmaxf(a0[0] + bb0.x, 0.0f) * ww0.x;  s1  = fmaxf(a1[0] + bb0.x, 0.0f) * ww0.x;
    s0 += fmaxf(a0[1] + bb0.y, 0.0f) * ww0.y;  s1 += fmaxf(a1[1] + bb0.y, 0.0f) * ww0.y;
    s0 += fmaxf(a0[2] + bb0.z, 0.0f) * ww0.z;  s1 += fmaxf(a1[2] + bb0.z, 0.0f) * ww0.z;
    s0 += fmaxf(a0[3] + bb0.w, 0.0f) * ww0.w;  s1 += fmaxf(a1[3] + bb0.w, 0.0f) * ww0.w;
    s0 += fmaxf(a0[4] + bb1.x, 0.0f) * ww1.x;  s1 += fmaxf(a1[4] + bb1.x, 0.0f) * ww1.x;
    s0 += fmaxf(a0[5] + bb1.y, 0.0f) * ww1.y;  s1 += fmaxf(a1[5] + bb1.y, 0.0f) * ww1.y;
    s0 += fmaxf(a0[6] + bb1.z, 0.0f) * ww1.z;  s1 += fmaxf(a1[6] + bb1.z, 0.0f) * ww1.z;
    s0 += fmaxf(a0[7] + bb1.w, 0.0f) * ww1.w;  s1 += fmaxf(a1[7] + bb1.w, 0.0f) * ww1.w;

    #pragma unroll
    for (int msk = 8; msk >= 1; msk >>= 1) {
        s0 += __shfl_xor(s0, msk, 64);
        s1 += __shfl_xor(s1, msk, 64);
    }
    if (jg == 0) {
        const float bias2 = b2[0];
        int row = r0 + ra;
        if (row < NROWS) {
            out[row] = 1.0f / (1.0f + __expf(-(s0 + bias2)));
            out[NROWS + row] = 1.0f;
        }
        row = r0 + rb;
        if (row < NROWS) {
            out[row] = 1.0f / (1.0f + __expf(-(s1 + bias2)));
            out[NROWS + row] = 1.0f;
        }
    }
}

// ---------------------------------------------------------------------------
extern "C" void kernel_launch(void* const* d_in, const int* in_sizes, int n_in,
                              void* d_out, int out_size, void* d_ws, size_t ws_size,
                              hipStream_t stream)
{
    const int*   idx       = (const int*)d_in[0];
    const int*   flg       = (const int*)d_in[1];
    const float* gaps      = (const float*)d_in[2];
    const float* item_emb  = (const float*)d_in[3];
    const float* ans_emb   = (const float*)d_in[4];
    const float* Wq        = (const float*)d_in[5];
    const float* bq        = (const float*)d_in[6];
    const float* Wk        = (const float*)d_in[7];
    const float* bk        = (const float*)d_in[8];
    const float* Wv        = (const float*)d_in[9];
    const float* bv        = (const float*)d_in[10];
    const float* Wh        = (const float*)d_in[11];
    const float* bh        = (const float*)d_in[12];
    const float* W1        = (const float*)d_in[13];
    const float* b1        = (const float*)d_in[14];
    const float* W2        = (const float*)d_in[15];
    const float* b2        = (const float*)d_in[16];
    const float* theta_raw = (const float*)d_in[17];

    float* ws  = (float*)d_ws;
    float* Qt  = ws;                           // 524288
    float* Kt  = Qt + BSZ * HN * SSZ * DN;     // 524288
    float* Vt  = Kt + BSZ * HN * SSZ * DN;     // 524288
    float* ec  = Vt + BSZ * HN * SSZ * DN;     // 524288
    float* srw = ec + BSZ * SSZ * EMBD;        // 16384
    float* Ep  = srw + BSZ * HN * SSZ;         // 16416
    float* Pp  = Ep + 16416;                   // 4128
    float* csw = Pp + 4128;                    // 4096*128
    (void)ws_size;

    float* out = (float*)d_out;

    embed2_kernel<<<BSZ * SSZ / TT, 256, 0, stream>>>(
        idx, flg, item_emb, ans_emb, Wq, bq, Wk, bk, Wv, bv, Wh, bh,
        Qt, Kt, Vt, ec, srw);
    scan_kernel<<<20, 1024, 0, stream>>>(srw, gaps, Ep, Pp);
    attn_mfma_kernel<<<BSZ * HN * 16, 256, 0, stream>>>(
        Qt, Kt, Vt, Ep, Pp, theta_raw, csw);
    mlp_kernel<<<(NROWS + 31) / 32, 256, 0, stream>>>(
        csw, ec, W1, b1, W2, b2, out);
}

// Round 6
// 158.542 us; speedup vs baseline: 4.0276x; 1.2680x over previous
//
#include <hip/hip_runtime.h>
#include <math.h>

#define BSZ 4
#define SSZ 1024
#define EMBD 128
#define HN 4
#define DN 32
#define TQ (SSZ - 1)      // 1023 queries per batch
#define NROWS (BSZ * TQ)  // 4092

typedef __attribute__((ext_vector_type(8))) short bf16x8;
typedef __attribute__((ext_vector_type(4))) short bf16x4;
typedef __attribute__((ext_vector_type(4))) float f32x4;

static __device__ __forceinline__ unsigned short f2bf(float x) {
    union { float f; unsigned u; } v; v.f = x;
    unsigned r = v.u + 0x7fffu + ((v.u >> 16) & 1u);   // RNE
    return (unsigned short)(r >> 16);
}
static __device__ __forceinline__ bf16x8 cvt8(const float4 a, const float4 b) {
    bf16x8 v;
    v[0] = (short)f2bf(a.x); v[1] = (short)f2bf(a.y);
    v[2] = (short)f2bf(a.z); v[3] = (short)f2bf(a.w);
    v[4] = (short)f2bf(b.x); v[5] = (short)f2bf(b.y);
    v[6] = (short)f2bf(b.z); v[7] = (short)f2bf(b.w);
    return v;
}

// ---------------------------------------------------------------------------
// Kernel 1: embed + project via MFMA. Block = 16 tokens, 256 threads, 4 waves.
// Wave w owns head w (output cols w*32..w*32+31 = n-tiles 2w,2w+1).
// MFMA 16x16x32 layouts (verified): A[m=lane&15][k=quad*8+j],
// B[n=lane&15][k=quad*8+j], C/D row=quad*4+reg, col=lane&15.
// Weight chunks (32 k x 128 n) staged transposed bf16 in LDS per phase.
// ---------------------------------------------------------------------------
__global__ __launch_bounds__(256)
void embed3_kernel(const int* __restrict__ idx, const int* __restrict__ flg,
                   const float* __restrict__ item_emb, const float* __restrict__ ans_emb,
                   const float* __restrict__ Wq, const float* __restrict__ bq,
                   const float* __restrict__ Wk, const float* __restrict__ bk,
                   const float* __restrict__ Wv, const float* __restrict__ bv,
                   const float* __restrict__ Wh, const float* __restrict__ bh_bias,
                   float* __restrict__ Qt, float* __restrict__ Kt, float* __restrict__ Vt,
                   float* __restrict__ ec, float* __restrict__ srw)
{
    __shared__ __align__(16) unsigned short esb[16][136];   // [tok][d] bf16, 272B rows
    __shared__ __align__(16) unsigned short asb[16][136];
    __shared__ __align__(16) unsigned short intb[16][136];
    __shared__ __align__(16) unsigned short Wt[128][40];    // [n][k-chunk 32] bf16, 80B rows

    const int tid = threadIdx.x;
    const int tok0 = blockIdx.x * 16;
    const int b = blockIdx.x >> 6;          // 64 blocks per batch
    const int s0 = tok0 & 1023;
    const int w = tid >> 6, lane = tid & 63;
    const int quad = lane >> 4, col = lane & 15;

    // ---- stage e, a (bf16) + ec (fp32) ----
    {
        const int tk = tid >> 4;            // 16 threads per token
        const int d0 = (tid & 15) * 8;
        const int tok = tok0 + tk;
        const float* esrc = item_emb + (size_t)idx[tok] * EMBD + d0;
        const float* asrc = ans_emb + (size_t)flg[tok] * EMBD + d0;
        const float4 e0 = *(const float4*)esrc;
        const float4 e1 = *(const float4*)(esrc + 4);
        const float4 a0 = *(const float4*)asrc;
        const float4 a1 = *(const float4*)(asrc + 4);
        *(float4*)(ec + (size_t)tok * EMBD + d0) = e0;
        *(float4*)(ec + (size_t)tok * EMBD + d0 + 4) = e1;
        *(bf16x8*)&esb[tk][d0] = cvt8(e0, e1);
        *(bf16x8*)&asb[tk][d0] = cvt8(a0, a1);
    }

    // weight chunk staging: rows src[0..32) x 128 cols -> Wt[n][k] transposed
    const int jb = (tid & 31) * 4;          // 4 output cols
    const int ib = (tid >> 5) * 4;          // 4 k-rows within chunk
    #define STAGE_W(SRC)                                                     \
    {                                                                        \
        float rr[4][4];                                                      \
        *(float4*)rr[0] = *(const float4*)((SRC) + (ib + 0) * 128 + jb);     \
        *(float4*)rr[1] = *(const float4*)((SRC) + (ib + 1) * 128 + jb);     \
        *(float4*)rr[2] = *(const float4*)((SRC) + (ib + 2) * 128 + jb);     \
        *(float4*)rr[3] = *(const float4*)((SRC) + (ib + 3) * 128 + jb);     \
        _Pragma("unroll")                                                    \
        for (int jj = 0; jj < 4; jj++) {                                     \
            bf16x4 v;                                                        \
            v[0] = (short)f2bf(rr[0][jj]); v[1] = (short)f2bf(rr[1][jj]);    \
            v[2] = (short)f2bf(rr[2][jj]); v[3] = (short)f2bf(rr[3][jj]);    \
            *(bf16x4*)&Wt[jb + jj][ib] = v;                                  \
        }                                                                    \
    }

    // ---- phase 1: inter = [e;a] @ Wh ----
    f32x4 accI[2] = {{0.f,0.f,0.f,0.f},{0.f,0.f,0.f,0.f}};
    for (int kc = 0; kc < 8; kc++) {
        __syncthreads();
        STAGE_W(Wh + (size_t)kc * 32 * 128);
        __syncthreads();
        const unsigned short (*Asrc)[136] = (kc < 4) ? esb : asb;
        const bf16x8 af = *(const bf16x8*)&Asrc[col][(kc & 3) * 32 + quad * 8];
        #pragma unroll
        for (int ntl = 0; ntl < 2; ntl++) {
            const bf16x8 bf = *(const bf16x8*)&Wt[w * 32 + ntl * 16 + col][quad * 8];
            accI[ntl] = __builtin_amdgcn_mfma_f32_16x16x32_bf16(af, bf, accI[ntl], 0, 0, 0);
        }
    }
    #pragma unroll
    for (int ntl = 0; ntl < 2; ntl++) {
        const int j = w * 32 + ntl * 16 + col;
        const float bb = bh_bias[j];
        #pragma unroll
        for (int r = 0; r < 4; r++)
            intb[quad * 4 + r][j] = f2bf(accI[ntl][r] + bb);
    }

    // ---- phase 2: Q = e@Wq, K = e@Wk ----
    f32x4 accQ[2] = {{0.f,0.f,0.f,0.f},{0.f,0.f,0.f,0.f}};
    f32x4 accK[2] = {{0.f,0.f,0.f,0.f},{0.f,0.f,0.f,0.f}};
    for (int kc = 0; kc < 4; kc++) {
        __syncthreads();
        STAGE_W(Wq + (size_t)kc * 32 * 128);
        __syncthreads();
        const bf16x8 af = *(const bf16x8*)&esb[col][kc * 32 + quad * 8];
        #pragma unroll
        for (int ntl = 0; ntl < 2; ntl++) {
            const bf16x8 bf = *(const bf16x8*)&Wt[w * 32 + ntl * 16 + col][quad * 8];
            accQ[ntl] = __builtin_amdgcn_mfma_f32_16x16x32_bf16(af, bf, accQ[ntl], 0, 0, 0);
        }
    }
    for (int kc = 0; kc < 4; kc++) {
        __syncthreads();
        STAGE_W(Wk + (size_t)kc * 32 * 128);
        __syncthreads();
        const bf16x8 af = *(const bf16x8*)&esb[col][kc * 32 + quad * 8];
        #pragma unroll
        for (int ntl = 0; ntl < 2; ntl++) {
            const bf16x8 bf = *(const bf16x8*)&Wt[w * 32 + ntl * 16 + col][quad * 8];
            accK[ntl] = __builtin_amdgcn_mfma_f32_16x16x32_bf16(af, bf, accK[ntl], 0, 0, 0);
        }
    }

    // ---- biases, sr, stores ----
    const int bhn = b * HN + w;
    {
        float p[4] = {0.f, 0.f, 0.f, 0.f};
        #pragma unroll
        for (int ntl = 0; ntl < 2; ntl++) {
            const int j = w * 32 + ntl * 16 + col;
            const float bQ = bq[j], bK = bk[j];
            #pragma unroll
            for (int r = 0; r < 4; r++) {
                const float qv = accQ[ntl][r] + bQ;
                const float kv = accK[ntl][r] + bK;
                const int s = s0 + quad * 4 + r;
                Qt[((size_t)bhn * SSZ + s) * DN + ntl * 16 + col] = qv;
                Kt[((size_t)bhn * SSZ + s) * DN + ntl * 16 + col] = kv;
                p[r] = fmaf(qv, kv, p[r]);
            }
        }
        #pragma unroll
        for (int r = 0; r < 4; r++) {
            float pr = p[r];
            pr += __shfl_xor(pr, 1, 64);
            pr += __shfl_xor(pr, 2, 64);
            pr += __shfl_xor(pr, 4, 64);
            pr += __shfl_xor(pr, 8, 64);
            if (col == 0)
                srw[(size_t)bhn * SSZ + s0 + quad * 4 + r] = pr * 0.17677669529663687f;
        }
    }

    // ---- phase 3: V = inter @ Wv ----
    f32x4 accV[2] = {{0.f,0.f,0.f,0.f},{0.f,0.f,0.f,0.f}};
    for (int kc = 0; kc < 4; kc++) {
        __syncthreads();
        STAGE_W(Wv + (size_t)kc * 32 * 128);
        __syncthreads();
        const bf16x8 af = *(const bf16x8*)&intb[col][kc * 32 + quad * 8];
        #pragma unroll
        for (int ntl = 0; ntl < 2; ntl++) {
            const bf16x8 bf = *(const bf16x8*)&Wt[w * 32 + ntl * 16 + col][quad * 8];
            accV[ntl] = __builtin_amdgcn_mfma_f32_16x16x32_bf16(af, bf, accV[ntl], 0, 0, 0);
        }
    }
    #pragma unroll
    for (int ntl = 0; ntl < 2; ntl++) {
        const int j = w * 32 + ntl * 16 + col;
        const float bV = bv[j];
        #pragma unroll
        for (int r = 0; r < 4; r++) {
            const int s = s0 + quad * 4 + r;
            Vt[((size_t)bhn * SSZ + s) * DN + ntl * 16 + col] = accV[ntl][r] + bV;
        }
    }
    #undef STAGE_W
}

// ---------------------------------------------------------------------------
// Kernel 2: scans. Blocks 0..15: Ep for bh. Blocks 16..19: Pp for b.
// ---------------------------------------------------------------------------
__global__ __launch_bounds__(1024)
void scan_kernel(const float* __restrict__ srw, const float* __restrict__ gaps,
                 float* __restrict__ Ep, float* __restrict__ Pp)
{
    __shared__ float buf[SSZ];
    __shared__ float red[16];
    const int tid = threadIdx.x;

    if (blockIdx.x < 16) {
        const int bh = blockIdx.x;
        float v = srw[bh * SSZ + tid];
        float wm = v;
        #pragma unroll
        for (int msk = 32; msk >= 1; msk >>= 1) wm = fmaxf(wm, __shfl_xor(wm, msk, 64));
        if ((tid & 63) == 0) red[tid >> 6] = wm;
        __syncthreads();
        if (tid == 0) {
            float mm = red[0];
            for (int k = 1; k < 16; k++) mm = fmaxf(mm, red[k]);
            red[0] = mm;
        }
        __syncthreads();
        const float mx = red[0];

        buf[tid] = __expf(v - mx);
        __syncthreads();
        for (int off = 1; off < SSZ; off <<= 1) {
            float tv = (tid >= off) ? buf[tid - off] : 0.0f;
            __syncthreads();
            buf[tid] += tv;
            __syncthreads();
        }
        Ep[bh * (SSZ + 1) + tid + 1] = buf[tid];
        if (tid == 0) Ep[bh * (SSZ + 1)] = 0.0f;
    } else {
        const int b = blockIdx.x - 16;
        buf[tid] = fmaxf(gaps[b * SSZ + tid], 1.0f);
        __syncthreads();
        for (int off = 1; off < SSZ; off <<= 1) {
            float tv = (tid >= off) ? buf[tid - off] : 0.0f;
            __syncthreads();
            buf[tid] += tv;
            __syncthreads();
        }
        Pp[b * (SSZ + 1) + tid + 1] = buf[tid];
        if (tid == 0) Pp[b * (SSZ + 1)] = 0.0f;
    }
}

// ---------------------------------------------------------------------------
// Kernel 3: MFMA attention (unchanged from R5).
// ---------------------------------------------------------------------------
__global__ __launch_bounds__(256)
void attn_mfma_kernel(const float* __restrict__ Qt, const float* __restrict__ Kt,
                      const float* __restrict__ Vt,
                      const float* __restrict__ Ep, const float* __restrict__ Pp,
                      const float* __restrict__ theta_raw, float* __restrict__ csw)
{
    __shared__ __align__(16) unsigned short Qs[64][40];
    __shared__ __align__(16) unsigned short Ks[64][40];
    __shared__ __align__(16) unsigned short Vs[32][72];
    __shared__ __align__(16) unsigned short Ps[4][16][72];
    __shared__ float EpS[SSZ + 1];
    __shared__ float PpS[SSZ + 1];

    const int bid = blockIdx.x;        // bh*16 + qt
    const int qt = bid & 15;
    const int bh = bid >> 4;
    const int b = bh >> 2, h = bh & 3;
    const int tid = threadIdx.x;
    const int w = tid >> 6, lane = tid & 63;
    const int quad = lane >> 4, col = lane & 15;
    const int t0 = qt * 64 + 1;
    const float scale = 0.17677669529663687f;

    {
        const float* Epb = Ep + bh * (SSZ + 1);
        const float* Ppb = Pp + b * (SSZ + 1);
        for (int x = tid; x <= SSZ; x += 256) { EpS[x] = Epb[x]; PpS[x] = Ppb[x]; }
    }
    {
        const int qq = tid >> 2;
        const int d0 = (tid & 3) * 8;
        int t = t0 + qq; if (t > 1023) t = 1023;
        const float* src = Qt + ((size_t)(bh * SSZ + t)) * DN + d0;
        bf16x8 v;
        #pragma unroll
        for (int k = 0; k < 8; k++) v[k] = (short)f2bf(src[k] * scale);
        *(bf16x8*)&Qs[qq][d0] = v;
    }
    __syncthreads();

    const float theta = logf(1.0f + __expf(theta_raw[h])) + 1e-4f;
    const float nth = -theta;
    float Ept[4], Ppt[4], iEp[4], tft[4];
    int qrow[4], tq[4];
    #pragma unroll
    for (int r = 0; r < 4; r++) {
        qrow[r] = w * 16 + quad * 4 + r;
        tq[r] = t0 + qrow[r];
        tft[r] = (float)tq[r];
        Ept[r] = EpS[tq[r]];
        Ppt[r] = PpS[tq[r]];
        iEp[r] = 1.0f / Ept[r];
    }

    const bf16x8 aq = *(const bf16x8*)&Qs[w * 16 + col][quad * 8];

    f32x4 acc0 = {0.f, 0.f, 0.f, 0.f};
    f32x4 acc1 = {0.f, 0.f, 0.f, 0.f};
    float lsum[4] = {0.f, 0.f, 0.f, 0.f};

    for (int c = 0; c <= qt; c++) {
        __syncthreads();
        {
            const int i = tid >> 2;
            const int d0 = (tid & 3) * 8;
            const float* src = Kt + ((size_t)(bh * SSZ + c * 64 + i)) * DN + d0;
            bf16x8 v;
            #pragma unroll
            for (int k = 0; k < 8; k++) v[k] = (short)f2bf(src[k]);
            *(bf16x8*)&Ks[i][d0] = v;
        }
        {
            const int i = tid >> 2;
            const int d0 = (tid & 3) * 8;
            const float* src = Vt + ((size_t)(bh * SSZ + c * 64 + i)) * DN + d0;
            #pragma unroll
            for (int k = 0; k < 8; k++) Vs[d0 + k][i] = f2bf(src[k]);
        }
        __syncthreads();

        const bool full = (c < qt);
        #pragma unroll
        for (int nt = 0; nt < 4; nt++) {
            const bf16x8 bk = *(const bf16x8*)&Ks[nt * 16 + col][quad * 8];
            f32x4 z = {0.f, 0.f, 0.f, 0.f};
            f32x4 raw = __builtin_amdgcn_mfma_f32_16x16x32_bf16(aq, bk, z, 0, 0, 0);
            const int il = nt * 16 + col;
            const int i_ = c * 64 + il;
            const float Epi = EpS[i_];
            const float Ppi = PpS[i_];
            const float fi = (float)i_;
            #pragma unroll
            for (int r = 0; r < 4; r++) {
                const float pdv = (tft[r] - fi) * (Ppt[r] - Ppi) * ((Ept[r] - Epi) * iEp[r]);
                const float sc  = raw[r] * __expf(nth * pdv);
                float p = __expf(sc);
                p = (full || il <= qrow[r]) ? p : 0.0f;
                lsum[r] += p;
                Ps[w][quad * 4 + r][il] = f2bf(p);
            }
        }
        #pragma unroll
        for (int ks = 0; ks < 2; ks++) {
            const bf16x8 ap = *(const bf16x8*)&Ps[w][col][ks * 32 + quad * 8];
            const bf16x8 bv0 = *(const bf16x8*)&Vs[col][ks * 32 + quad * 8];
            const bf16x8 bv1 = *(const bf16x8*)&Vs[16 + col][ks * 32 + quad * 8];
            acc0 = __builtin_amdgcn_mfma_f32_16x16x32_bf16(ap, bv0, acc0, 0, 0, 0);
            acc1 = __builtin_amdgcn_mfma_f32_16x16x32_bf16(ap, bv1, acc1, 0, 0, 0);
        }
    }

    #pragma unroll
    for (int r = 0; r < 4; r++) {
        float lr = lsum[r];
        #pragma unroll
        for (int msk = 8; msk >= 1; msk >>= 1) lr += __shfl_xor(lr, msk, 64);
        lsum[r] = 1.0f / lr;
    }

    #pragma unroll
    for (int r = 0; r < 4; r++) {
        if (tq[r] <= 1023) {
            float* dst = csw + ((size_t)(b * TQ + (tq[r] - 1))) * EMBD + h * DN;
            dst[col]      = acc0[r] * lsum[r];
            dst[16 + col] = acc1[r] * lsum[r];
        }
    }
}

// ---------------------------------------------------------------------------
// Kernel 4: MLP via MFMA. Block = 32 rows, 256 threads, 4 waves.
// Wave w = (mt = w&1 -> rows mt*16..+16, nh = w>>1 -> n-tiles nh*4..+4).
// W1^T and feat staged bf16 in LDS once. h1.W2 folded into C-epilogue.
// ---------------------------------------------------------------------------
__global__ __launch_bounds__(256)
void mlp3_kernel(const float* __restrict__ csw, const float* __restrict__ ec,
                 const float* __restrict__ W1, const float* __restrict__ b1,
                 const float* __restrict__ W2, const float* __restrict__ b2,
                 float* __restrict__ out)
{
    __shared__ __align__(16) unsigned short featb[32][264];  // [row][k 256] 528B rows
    __shared__ __align__(16) unsigned short W1t[128][264];   // [n][k 256]
    __shared__ float sred[4][16];

    const int tid = threadIdx.x;
    const int r0 = blockIdx.x * 32;
    const int w = tid >> 6, lane = tid & 63;
    const int quad = lane >> 4, col = lane & 15;
    const int mt = w & 1, nh = w >> 1;

    // ---- stage W1^T (256x128 fp32 -> [n][k] bf16) ----
    {
        const int jb = (tid & 31) * 4;
        const int ib = (tid >> 5) * 4;
        for (int ic = 0; ic < 8; ic++) {
            const int i0 = ic * 32 + ib;
            float rr[4][4];
            *(float4*)rr[0] = *(const float4*)(W1 + (size_t)(i0 + 0) * 128 + jb);
            *(float4*)rr[1] = *(const float4*)(W1 + (size_t)(i0 + 1) * 128 + jb);
            *(float4*)rr[2] = *(const float4*)(W1 + (size_t)(i0 + 2) * 128 + jb);
            *(float4*)rr[3] = *(const float4*)(W1 + (size_t)(i0 + 3) * 128 + jb);
            #pragma unroll
            for (int jj = 0; jj < 4; jj++) {
                bf16x4 v;
                v[0] = (short)f2bf(rr[0][jj]); v[1] = (short)f2bf(rr[1][jj]);
                v[2] = (short)f2bf(rr[2][jj]); v[3] = (short)f2bf(rr[3][jj]);
                *(bf16x4*)&W1t[jb + jj][i0] = v;
            }
        }
    }
    // ---- stage feat = [ctx(128); e(128)] bf16 ----
    {
        const int rr = tid >> 3;
        const int c0 = (tid & 7) * 32;
        int row = r0 + rr; if (row >= NROWS) row = NROWS - 1;
        const float* src;
        if (c0 < 128) {
            src = csw + (size_t)row * EMBD + c0;
        } else {
            const int bb = row / TQ;
            const int tt = row - bb * TQ + 1;
            src = ec + ((size_t)(bb * SSZ + tt)) * EMBD + (c0 - 128);
        }
        #pragma unroll
        for (int g = 0; g < 4; g++) {
            const float4 f0 = ((const float4*)src)[g * 2];
            const float4 f1 = ((const float4*)src)[g * 2 + 1];
            *(bf16x8*)&featb[rr][c0 + g * 8] = cvt8(f0, f1);
        }
    }
    __syncthreads();

    // ---- GEMM + fused epilogue ----
    float s[4] = {0.f, 0.f, 0.f, 0.f};
    #pragma unroll
    for (int ntl = 0; ntl < 4; ntl++) {
        const int nt = nh * 4 + ntl;
        f32x4 acc = {0.f, 0.f, 0.f, 0.f};
        #pragma unroll
        for (int kc = 0; kc < 8; kc++) {
            const bf16x8 af = *(const bf16x8*)&featb[mt * 16 + col][kc * 32 + quad * 8];
            const bf16x8 bf = *(const bf16x8*)&W1t[nt * 16 + col][kc * 32 + quad * 8];
            acc = __builtin_amdgcn_mfma_f32_16x16x32_bf16(af, bf, acc, 0, 0, 0);
        }
        const int j = nt * 16 + col;
        const float b1j = b1[j], w2j = W2[j];
        #pragma unroll
        for (int r = 0; r < 4; r++)
            s[r] = fmaf(fmaxf(acc[r] + b1j, 0.0f), w2j, s[r]);
    }
    #pragma unroll
    for (int r = 0; r < 4; r++) {
        float sr = s[r];
        sr += __shfl_xor(sr, 1, 64);
        sr += __shfl_xor(sr, 2, 64);
        sr += __shfl_xor(sr, 4, 64);
        sr += __shfl_xor(sr, 8, 64);
        if (col == 0) sred[w][quad * 4 + r] = sr;
    }
    __syncthreads();
    if (tid < 32) {
        const int mt2 = tid >> 4, rr = tid & 15;
        const float logit = sred[mt2][rr] + sred[mt2 + 2][rr] + b2[0];
        const int grow = r0 + tid;
        if (grow < NROWS) {
            out[grow] = 1.0f / (1.0f + __expf(-logit));
            out[NROWS + grow] = 1.0f;
        }
    }
}

// ---------------------------------------------------------------------------
extern "C" void kernel_launch(void* const* d_in, const int* in_sizes, int n_in,
                              void* d_out, int out_size, void* d_ws, size_t ws_size,
                              hipStream_t stream)
{
    const int*   idx       = (const int*)d_in[0];
    const int*   flg       = (const int*)d_in[1];
    const float* gaps      = (const float*)d_in[2];
    const float* item_emb  = (const float*)d_in[3];
    const float* ans_emb   = (const float*)d_in[4];
    const float* Wq        = (const float*)d_in[5];
    const float* bq        = (const float*)d_in[6];
    const float* Wk        = (const float*)d_in[7];
    const float* bk        = (const float*)d_in[8];
    const float* Wv        = (const float*)d_in[9];
    const float* bv        = (const float*)d_in[10];
    const float* Wh        = (const float*)d_in[11];
    const float* bh        = (const float*)d_in[12];
    const float* W1        = (const float*)d_in[13];
    const float* b1        = (const float*)d_in[14];
    const float* W2        = (const float*)d_in[15];
    const float* b2        = (const float*)d_in[16];
    const float* theta_raw = (const float*)d_in[17];

    float* ws  = (float*)d_ws;
    float* Qt  = ws;                           // 524288
    float* Kt  = Qt + BSZ * HN * SSZ * DN;     // 524288
    float* Vt  = Kt + BSZ * HN * SSZ * DN;     // 524288
    float* ec  = Vt + BSZ * HN * SSZ * DN;     // 524288
    float* srw = ec + BSZ * SSZ * EMBD;        // 16384
    float* Ep  = srw + BSZ * HN * SSZ;         // 16416
    float* Pp  = Ep + 16416;                   // 4128
    float* csw = Pp + 4128;                    // 4096*128
    (void)ws_size;

    float* out = (float*)d_out;

    embed3_kernel<<<BSZ * SSZ / 16, 256, 0, stream>>>(
        idx, flg, item_emb, ans_emb, Wq, bq, Wk, bk, Wv, bv, Wh, bh,
        Qt, Kt, Vt, ec, srw);
    scan_kernel<<<20, 1024, 0, stream>>>(srw, gaps, Ep, Pp);
    attn_mfma_kernel<<<BSZ * HN * 16, 256, 0, stream>>>(
        Qt, Kt, Vt, Ep, Pp, theta_raw, csw);
    mlp3_kernel<<<(NROWS + 31) / 32, 256, 0, stream>>>(
        csw, ec, W1, b1, W2, b2, out);
}

// Round 7
// 149.449 us; speedup vs baseline: 4.2727x; 1.0608x over previous
//
#include <hip/hip_runtime.h>
#include <math.h>

#define BSZ 4
#define SSZ 1024
#define EMBD 128
#define HN 4
#define DN 32
#define TQ (SSZ - 1)      // 1023 queries per batch
#define NROWS (BSZ * TQ)  // 4092

typedef __attribute__((ext_vector_type(8))) short bf16x8;
typedef __attribute__((ext_vector_type(4))) short bf16x4;
typedef __attribute__((ext_vector_type(4))) float f32x4;

static __device__ __forceinline__ unsigned short f2bf(float x) {
    union { float f; unsigned u; } v; v.f = x;
    unsigned r = v.u + 0x7fffu + ((v.u >> 16) & 1u);   // RNE
    return (unsigned short)(r >> 16);
}
static __device__ __forceinline__ bf16x8 cvt8(const float4 a, const float4 b) {
    bf16x8 v;
    v[0] = (short)f2bf(a.x); v[1] = (short)f2bf(a.y);
    v[2] = (short)f2bf(a.z); v[3] = (short)f2bf(a.w);
    v[4] = (short)f2bf(b.x); v[5] = (short)f2bf(b.y);
    v[6] = (short)f2bf(b.z); v[7] = (short)f2bf(b.w);
    return v;
}

// ---------------------------------------------------------------------------
// Kernel 1: embed + project via MFMA, pipelined weight staging.
// Block = 16 tokens, 256 threads, wave w = head w.
// 20 weight-chunk rounds: r<8 Wh (A=e then a), 8..11 Wq, 12..15 Wk, 16..19 Wv.
// Chunk r+1 is prefetched into registers during round r's MFMAs.
// Outputs Q(bf16, xscale), K(bf16), V(bf16) in [bh][s][d]; ec fp32; sr fp32.
// ---------------------------------------------------------------------------
__global__ __launch_bounds__(256)
void embed4_kernel(const int* __restrict__ idx, const int* __restrict__ flg,
                   const float* __restrict__ item_emb, const float* __restrict__ ans_emb,
                   const float* __restrict__ Wq, const float* __restrict__ bq,
                   const float* __restrict__ Wk, const float* __restrict__ bk,
                   const float* __restrict__ Wv, const float* __restrict__ bv,
                   const float* __restrict__ Wh, const float* __restrict__ bh_bias,
                   unsigned short* __restrict__ Qts, unsigned short* __restrict__ Kts,
                   unsigned short* __restrict__ Vts,
                   float* __restrict__ ec, float* __restrict__ srw)
{
    __shared__ __align__(16) unsigned short esb[16][136];
    __shared__ __align__(16) unsigned short asb[16][136];
    __shared__ __align__(16) unsigned short intb[16][136];
    __shared__ __align__(16) unsigned short Wt[128][40];

    const int tid = threadIdx.x;
    const int tok0 = blockIdx.x * 16;
    const int b = blockIdx.x >> 6;
    const int s0 = tok0 & 1023;
    const int w = tid >> 6, lane = tid & 63;
    const int quad = lane >> 4, col = lane & 15;

    // ---- stage e, a (bf16) + ec (fp32) ----
    {
        const int tk = tid >> 4;
        const int d0 = (tid & 15) * 8;
        const int tok = tok0 + tk;
        const float* esrc = item_emb + (size_t)idx[tok] * EMBD + d0;
        const float* asrc = ans_emb + (size_t)flg[tok] * EMBD + d0;
        const float4 e0 = *(const float4*)esrc;
        const float4 e1 = *(const float4*)(esrc + 4);
        const float4 a0 = *(const float4*)asrc;
        const float4 a1 = *(const float4*)(asrc + 4);
        *(float4*)(ec + (size_t)tok * EMBD + d0) = e0;
        *(float4*)(ec + (size_t)tok * EMBD + d0 + 4) = e1;
        *(bf16x8*)&esb[tk][d0] = cvt8(e0, e1);
        *(bf16x8*)&asb[tk][d0] = cvt8(a0, a1);
    }

    const int jb = (tid & 31) * 4;
    const int ib = (tid >> 5) * 4;
    float rr[4][4];

    #define WSRC(R) ((R) < 8 ? Wh + (size_t)(R) * 4096                     \
                  : (R) < 12 ? Wq + (size_t)((R) - 8) * 4096               \
                  : (R) < 16 ? Wk + (size_t)((R) - 12) * 4096              \
                  : Wv + (size_t)((R) - 16) * 4096)
    #define LOADW(P)                                                       \
    {                                                                      \
        const float* _p = (P);                                             \
        *(float4*)rr[0] = *(const float4*)(_p + (ib + 0) * 128 + jb);      \
        *(float4*)rr[1] = *(const float4*)(_p + (ib + 1) * 128 + jb);      \
        *(float4*)rr[2] = *(const float4*)(_p + (ib + 2) * 128 + jb);      \
        *(float4*)rr[3] = *(const float4*)(_p + (ib + 3) * 128 + jb);      \
    }
    #define STOREW                                                         \
    {                                                                      \
        _Pragma("unroll")                                                  \
        for (int jj = 0; jj < 4; jj++) {                                   \
            bf16x4 v;                                                      \
            v[0] = (short)f2bf(rr[0][jj]); v[1] = (short)f2bf(rr[1][jj]);  \
            v[2] = (short)f2bf(rr[2][jj]); v[3] = (short)f2bf(rr[3][jj]);  \
            *(bf16x4*)&Wt[jb + jj][ib] = v;                                \
        }                                                                  \
    }

    f32x4 accI[2] = {{0.f,0.f,0.f,0.f},{0.f,0.f,0.f,0.f}};
    f32x4 accQ[2] = {{0.f,0.f,0.f,0.f},{0.f,0.f,0.f,0.f}};
    f32x4 accK[2] = {{0.f,0.f,0.f,0.f},{0.f,0.f,0.f,0.f}};
    f32x4 accV[2] = {{0.f,0.f,0.f,0.f},{0.f,0.f,0.f,0.f}};

    LOADW(WSRC(0));
    #pragma unroll
    for (int r = 0; r < 20; r++) {
        __syncthreads();
        STOREW;
        __syncthreads();
        if (r < 19) LOADW(WSRC(r + 1));        // prefetch next chunk (overlaps MFMA)

        const unsigned short (*Ab)[136] = (r < 4) ? esb : (r < 8) ? asb
                                        : (r < 16) ? esb : intb;
        const int koff = ((r < 8) ? (r & 3) : (r < 12) ? (r - 8)
                        : (r < 16) ? (r - 12) : (r - 16)) * 32;
        const bf16x8 af = *(const bf16x8*)&Ab[col][koff + quad * 8];
        f32x4* acc = (r < 8) ? accI : (r < 12) ? accQ : (r < 16) ? accK : accV;
        #pragma unroll
        for (int ntl = 0; ntl < 2; ntl++) {
            const bf16x8 bf = *(const bf16x8*)&Wt[w * 32 + ntl * 16 + col][quad * 8];
            acc[ntl] = __builtin_amdgcn_mfma_f32_16x16x32_bf16(af, bf, acc[ntl], 0, 0, 0);
        }
        if (r == 7) {   // inter ready -> intb (visible via round-8 barriers)
            #pragma unroll
            for (int ntl = 0; ntl < 2; ntl++) {
                const int j = w * 32 + ntl * 16 + col;
                const float bb = bh_bias[j];
                #pragma unroll
                for (int r4 = 0; r4 < 4; r4++)
                    intb[quad * 4 + r4][j] = f2bf(accI[ntl][r4] + bb);
            }
        }
    }
    #undef LOADW
    #undef STOREW
    #undef WSRC

    // ---- epilogue: biases, sr, bf16 stores ----
    const int bhn = b * HN + w;
    const float scale = 0.17677669529663687f;
    float p[4] = {0.f, 0.f, 0.f, 0.f};
    #pragma unroll
    for (int ntl = 0; ntl < 2; ntl++) {
        const int j = w * 32 + ntl * 16 + col;
        const float bQ = bq[j], bK = bk[j], bV = bv[j];
        #pragma unroll
        for (int r = 0; r < 4; r++) {
            const float qv = accQ[ntl][r] + bQ;
            const float kv = accK[ntl][r] + bK;
            const int s = s0 + quad * 4 + r;
            const size_t o = ((size_t)bhn * SSZ + s) * DN + ntl * 16 + col;
            Qts[o] = f2bf(qv * scale);
            Kts[o] = f2bf(kv);
            Vts[o] = f2bf(accV[ntl][r] + bV);
            p[r] = fmaf(qv, kv, p[r]);
        }
    }
    #pragma unroll
    for (int r = 0; r < 4; r++) {
        float pr = p[r];
        pr += __shfl_xor(pr, 1, 64);
        pr += __shfl_xor(pr, 2, 64);
        pr += __shfl_xor(pr, 4, 64);
        pr += __shfl_xor(pr, 8, 64);
        if (col == 0)
            srw[(size_t)bhn * SSZ + s0 + quad * 4 + r] = pr * scale;
    }
}

// ---------------------------------------------------------------------------
// Kernel 2: fused scan + MFMA attention. Block = (bh, qtile of 64). 4 waves.
// Phase 0: in-block Ep = cumsum(exp(sr)) (max cancels in the rel ratio) and
// Pp = cumsum(max(gaps,1)) via wave scans. Then flash loop with K/V register
// prefetch (chunk c+1 loads overlap chunk c compute).
// ---------------------------------------------------------------------------
__global__ __launch_bounds__(256)
void attn4_kernel(const unsigned short* __restrict__ Qts,
                  const unsigned short* __restrict__ Kts,
                  const unsigned short* __restrict__ Vts,
                  const float* __restrict__ srw, const float* __restrict__ gaps,
                  const float* __restrict__ theta_raw, float* __restrict__ csw)
{
    __shared__ __align__(16) unsigned short Ks[64][40];
    __shared__ __align__(16) unsigned short Vs[32][72];
    __shared__ __align__(16) unsigned short Ps[4][16][72];
    __shared__ float EpS[SSZ + 1];
    __shared__ float PpS[SSZ + 1];
    __shared__ float wtot[4];

    const int bid = blockIdx.x;        // bh*16 + qt
    const int qt = bid & 15;
    const int bh = bid >> 4;
    const int b = bh >> 2, h = bh & 3;
    const int tid = threadIdx.x;
    const int w = tid >> 6, lane = tid & 63;
    const int quad = lane >> 4, col = lane & 15;
    const int t0 = qt * 64 + 1;

    // ---- phase 0a: Ep scan (1024 elems, 4/thread) ----
    {
        const float4 sv = *(const float4*)(srw + (size_t)bh * SSZ + tid * 4);
        const float e0 = __expf(sv.x);
        const float p0 = e0;
        const float p1 = p0 + __expf(sv.y);
        const float p2 = p1 + __expf(sv.z);
        const float p3 = p2 + __expf(sv.w);
        float s = p3;
        #pragma unroll
        for (int d = 1; d < 64; d <<= 1) {
            const float t = __shfl_up(s, d, 64);
            if (lane >= d) s += t;
        }
        if (lane == 63) wtot[w] = s;
        __syncthreads();
        float base = s - p3;
        for (int ww = 0; ww < w; ww++) base += wtot[ww];
        EpS[tid * 4 + 1] = base + p0;
        EpS[tid * 4 + 2] = base + p1;
        EpS[tid * 4 + 3] = base + p2;
        EpS[tid * 4 + 4] = base + p3;
        if (tid == 0) EpS[0] = 0.0f;
    }
    // ---- phase 0b: Pp scan ----
    {
        const float4 gv = *(const float4*)(gaps + (size_t)b * SSZ + tid * 4);
        const float p0 = fmaxf(gv.x, 1.0f);
        const float p1 = p0 + fmaxf(gv.y, 1.0f);
        const float p2 = p1 + fmaxf(gv.z, 1.0f);
        const float p3 = p2 + fmaxf(gv.w, 1.0f);
        float s = p3;
        #pragma unroll
        for (int d = 1; d < 64; d <<= 1) {
            const float t = __shfl_up(s, d, 64);
            if (lane >= d) s += t;
        }
        __syncthreads();               // all wtot reads from 0a done
        if (lane == 63) wtot[w] = s;
        __syncthreads();
        float base = s - p3;
        for (int ww = 0; ww < w; ww++) base += wtot[ww];
        PpS[tid * 4 + 1] = base + p0;
        PpS[tid * 4 + 2] = base + p1;
        PpS[tid * 4 + 3] = base + p2;
        PpS[tid * 4 + 4] = base + p3;
        if (tid == 0) PpS[0] = 0.0f;
    }
    __syncthreads();

    // ---- per-lane invariants ----
    const float theta = logf(1.0f + __expf(theta_raw[h])) + 1e-4f;
    const float nth = -theta;
    float Ept[4], Ppt[4], iEp[4], tft[4];
    int qrow[4], tq[4];
    #pragma unroll
    for (int r = 0; r < 4; r++) {
        qrow[r] = w * 16 + quad * 4 + r;
        tq[r] = t0 + qrow[r];
        tft[r] = (float)tq[r];
        Ept[r] = EpS[tq[r]];
        Ppt[r] = PpS[tq[r]];
        iEp[r] = 1.0f / Ept[r];
    }

    // ---- Q A-frag direct from global (bf16, pre-scaled) ----
    bf16x8 aq;
    {
        int t = t0 + w * 16 + col; if (t > 1023) t = 1023;
        aq = *(const bf16x8*)(Qts + ((size_t)(bh * SSZ + t)) * DN + quad * 8);
    }

    f32x4 acc0 = {0.f, 0.f, 0.f, 0.f};
    f32x4 acc1 = {0.f, 0.f, 0.f, 0.f};
    float lsum[4] = {0.f, 0.f, 0.f, 0.f};

    const int i_st = tid >> 2;
    const int d0 = (tid & 3) * 8;
    bf16x8 kreg = *(const bf16x8*)(Kts + ((size_t)(bh * SSZ + i_st)) * DN + d0);
    bf16x8 vreg = *(const bf16x8*)(Vts + ((size_t)(bh * SSZ + i_st)) * DN + d0);

    for (int c = 0; c <= qt; c++) {
        __syncthreads();               // previous chunk consumed
        *(bf16x8*)&Ks[i_st][d0] = kreg;
        #pragma unroll
        for (int k2 = 0; k2 < 8; k2++) Vs[d0 + k2][i_st] = (unsigned short)vreg[k2];
        __syncthreads();
        if (c < qt) {                  // prefetch next chunk (overlaps compute)
            const size_t o = ((size_t)(bh * SSZ + (c + 1) * 64 + i_st)) * DN + d0;
            kreg = *(const bf16x8*)(Kts + o);
            vreg = *(const bf16x8*)(Vts + o);
        }

        const bool full = (c < qt);
        #pragma unroll
        for (int nt = 0; nt < 4; nt++) {
            const bf16x8 bk = *(const bf16x8*)&Ks[nt * 16 + col][quad * 8];
            f32x4 z = {0.f, 0.f, 0.f, 0.f};
            f32x4 raw = __builtin_amdgcn_mfma_f32_16x16x32_bf16(aq, bk, z, 0, 0, 0);
            const int il = nt * 16 + col;
            const int i_ = c * 64 + il;
            const float Epi = EpS[i_];
            const float Ppi = PpS[i_];
            const float fi = (float)i_;
            #pragma unroll
            for (int r = 0; r < 4; r++) {
                const float pdv = (tft[r] - fi) * (Ppt[r] - Ppi) * ((Ept[r] - Epi) * iEp[r]);
                const float sc  = raw[r] * __expf(nth * pdv);
                float p = __expf(sc);
                p = (full || il <= qrow[r]) ? p : 0.0f;
                lsum[r] += p;
                Ps[w][quad * 4 + r][il] = f2bf(p);
            }
        }
        #pragma unroll
        for (int ks = 0; ks < 2; ks++) {
            const bf16x8 ap = *(const bf16x8*)&Ps[w][col][ks * 32 + quad * 8];
            const bf16x8 bv0 = *(const bf16x8*)&Vs[col][ks * 32 + quad * 8];
            const bf16x8 bv1 = *(const bf16x8*)&Vs[16 + col][ks * 32 + quad * 8];
            acc0 = __builtin_amdgcn_mfma_f32_16x16x32_bf16(ap, bv0, acc0, 0, 0, 0);
            acc1 = __builtin_amdgcn_mfma_f32_16x16x32_bf16(ap, bv1, acc1, 0, 0, 0);
        }
    }

    #pragma unroll
    for (int r = 0; r < 4; r++) {
        float lr = lsum[r];
        #pragma unroll
        for (int msk = 8; msk >= 1; msk >>= 1) lr += __shfl_xor(lr, msk, 64);
        lsum[r] = 1.0f / lr;
    }
    #pragma unroll
    for (int r = 0; r < 4; r++) {
        if (tq[r] <= 1023) {
            float* dst = csw + ((size_t)(b * TQ + (tq[r] - 1))) * EMBD + h * DN;
            dst[col]      = acc0[r] * lsum[r];
            dst[16 + col] = acc1[r] * lsum[r];
        }
    }
}

// ---------------------------------------------------------------------------
// Kernel 3: MLP via MFMA (unchanged from R6).
// ---------------------------------------------------------------------------
__global__ __launch_bounds__(256)
void mlp3_kernel(const float* __restrict__ csw, const float* __restrict__ ec,
                 const float* __restrict__ W1, const float* __restrict__ b1,
                 const float* __restrict__ W2, const float* __restrict__ b2,
                 float* __restrict__ out)
{
    __shared__ __align__(16) unsigned short featb[32][264];
    __shared__ __align__(16) unsigned short W1t[128][264];
    __shared__ float sred[4][16];

    const int tid = threadIdx.x;
    const int r0 = blockIdx.x * 32;
    const int w = tid >> 6, lane = tid & 63;
    const int quad = lane >> 4, col = lane & 15;
    const int mt = w & 1, nh = w >> 1;

    {
        const int jb = (tid & 31) * 4;
        const int ib = (tid >> 5) * 4;
        for (int ic = 0; ic < 8; ic++) {
            const int i0 = ic * 32 + ib;
            float rr[4][4];
            *(float4*)rr[0] = *(const float4*)(W1 + (size_t)(i0 + 0) * 128 + jb);
            *(float4*)rr[1] = *(const float4*)(W1 + (size_t)(i0 + 1) * 128 + jb);
            *(float4*)rr[2] = *(const float4*)(W1 + (size_t)(i0 + 2) * 128 + jb);
            *(float4*)rr[3] = *(const float4*)(W1 + (size_t)(i0 + 3) * 128 + jb);
            #pragma unroll
            for (int jj = 0; jj < 4; jj++) {
                bf16x4 v;
                v[0] = (short)f2bf(rr[0][jj]); v[1] = (short)f2bf(rr[1][jj]);
                v[2] = (short)f2bf(rr[2][jj]); v[3] = (short)f2bf(rr[3][jj]);
                *(bf16x4*)&W1t[jb + jj][i0] = v;
            }
        }
    }
    {
        const int rr = tid >> 3;
        const int c0 = (tid & 7) * 32;
        int row = r0 + rr; if (row >= NROWS) row = NROWS - 1;
        const float* src;
        if (c0 < 128) {
            src = csw + (size_t)row * EMBD + c0;
        } else {
            const int bb = row / TQ;
            const int tt = row - bb * TQ + 1;
            src = ec + ((size_t)(bb * SSZ + tt)) * EMBD + (c0 - 128);
        }
        #pragma unroll
        for (int g = 0; g < 4; g++) {
            const float4 f0 = ((const float4*)src)[g * 2];
            const float4 f1 = ((const float4*)src)[g * 2 + 1];
            *(bf16x8*)&featb[rr][c0 + g * 8] = cvt8(f0, f1);
        }
    }
    __syncthreads();

    float s[4] = {0.f, 0.f, 0.f, 0.f};
    #pragma unroll
    for (int ntl = 0; ntl < 4; ntl++) {
        const int nt = nh * 4 + ntl;
        f32x4 acc = {0.f, 0.f, 0.f, 0.f};
        #pragma unroll
        for (int kc = 0; kc < 8; kc++) {
            const bf16x8 af = *(const bf16x8*)&featb[mt * 16 + col][kc * 32 + quad * 8];
            const bf16x8 bf = *(const bf16x8*)&W1t[nt * 16 + col][kc * 32 + quad * 8];
            acc = __builtin_amdgcn_mfma_f32_16x16x32_bf16(af, bf, acc, 0, 0, 0);
        }
        const int j = nt * 16 + col;
        const float b1j = b1[j], w2j = W2[j];
        #pragma unroll
        for (int r = 0; r < 4; r++)
            s[r] = fmaf(fmaxf(acc[r] + b1j, 0.0f), w2j, s[r]);
    }
    #pragma unroll
    for (int r = 0; r < 4; r++) {
        float sr = s[r];
        sr += __shfl_xor(sr, 1, 64);
        sr += __shfl_xor(sr, 2, 64);
        sr += __shfl_xor(sr, 4, 64);
        sr += __shfl_xor(sr, 8, 64);
        if (col == 0) sred[w][quad * 4 + r] = sr;
    }
    __syncthreads();
    if (tid < 32) {
        const int mt2 = tid >> 4, rr = tid & 15;
        const float logit = sred[mt2][rr] + sred[mt2 + 2][rr] + b2[0];
        const int grow = r0 + tid;
        if (grow < NROWS) {
            out[grow] = 1.0f / (1.0f + __expf(-logit));
            out[NROWS + grow] = 1.0f;
        }
    }
}

// ---------------------------------------------------------------------------
extern "C" void kernel_launch(void* const* d_in, const int* in_sizes, int n_in,
                              void* d_out, int out_size, void* d_ws, size_t ws_size,
                              hipStream_t stream)
{
    const int*   idx       = (const int*)d_in[0];
    const int*   flg       = (const int*)d_in[1];
    const float* gaps      = (const float*)d_in[2];
    const float* item_emb  = (const float*)d_in[3];
    const float* ans_emb   = (const float*)d_in[4];
    const float* Wq        = (const float*)d_in[5];
    const float* bq        = (const float*)d_in[6];
    const float* Wk        = (const float*)d_in[7];
    const float* bk        = (const float*)d_in[8];
    const float* Wv        = (const float*)d_in[9];
    const float* bv        = (const float*)d_in[10];
    const float* Wh        = (const float*)d_in[11];
    const float* bh        = (const float*)d_in[12];
    const float* W1        = (const float*)d_in[13];
    const float* b1        = (const float*)d_in[14];
    const float* W2        = (const float*)d_in[15];
    const float* b2        = (const float*)d_in[16];
    const float* theta_raw = (const float*)d_in[17];
    (void)in_sizes; (void)n_in; (void)ws_size;

    const size_t QKV = (size_t)BSZ * HN * SSZ * DN;   // 524288 elements
    unsigned short* Qts = (unsigned short*)d_ws;
    unsigned short* Kts = Qts + QKV;
    unsigned short* Vts = Kts + QKV;
    float* ec  = (float*)(Vts + QKV);                 // 3 MB offset, aligned
    float* srw = ec + (size_t)BSZ * SSZ * EMBD;
    float* csw = srw + (size_t)BSZ * HN * SSZ;

    float* out = (float*)d_out;

    embed4_kernel<<<BSZ * SSZ / 16, 256, 0, stream>>>(
        idx, flg, item_emb, ans_emb, Wq, bq, Wk, bk, Wv, bv, Wh, bh,
        Qts, Kts, Vts, ec, srw);
    attn4_kernel<<<BSZ * HN * 16, 256, 0, stream>>>(
        Qts, Kts, Vts, srw, gaps, theta_raw, csw);
    mlp3_kernel<<<(NROWS + 31) / 32, 256, 0, stream>>>(
        csw, ec, W1, b1, W2, b2, out);
}